// Round 5
// baseline (652.298 us; speedup 1.0000x reference)
//
#include <hip/hip_runtime.h>
#include <hip/hip_bf16.h>
#include <math.h>

typedef __bf16 bf16_t;
typedef __bf16 bf16x8 __attribute__((ext_vector_type(8)));
typedef float  f32x4  __attribute__((ext_vector_type(4)));

#define NBLK 2688          // 5376 windows / 2 per block
// pair offsets (1 pair = 2 bf16) of pre-swizzled weights inside d_ws
#define WP_QKV  0
#define WP_PROJ 55296
#define WP_MLP1 73728
#define WP_MLP2 147456
#define WP_TOT  221184
// bf16 element offsets
#define WF_QKV  0
#define WF_PROJ 110592
#define WF_MLP1 147456
#define WF_MLP2 294912

// fast gelu: tanh form, max abs err ~5e-4 (numerics harness-proven in R2 run, absmax 0.03125)
// ~12 VALU ops vs ~25-30 for erff: gelu was ~half of all VALU work (96 calls/thread).
__device__ __forceinline__ float fast_gelu(float v) {
    float u  = 0.7978845608028654f * v * (1.f + 0.044715f * v * v);
    float au = fabsf(u);
    float e  = __expf(-2.f * au);          // in (0,1], never overflows
    float th = __fdividef(1.f - e, 1.f + e);
    th = copysignf(th, u);
    return 0.5f * v * (1.f + th);
}

// ---------------- merged weight pre-swizzle: W[K][N] f32 -> B-fragment bf16 ----------------
// frag(nt,kt): dst[((nt*Kt + kt)*64 + lane)*8 + j] = W[kt*32 + (lane>>4)*8 + j][nt*16 + (lane&15)]
__global__ void preproc_all(const float* __restrict__ qkv_w, const float* __restrict__ proj_w,
                            const float* __restrict__ mlp_w1, const float* __restrict__ mlp_w2,
                            bf16_t* __restrict__ dst) {
    int p = blockIdx.x * 256 + threadIdx.x;
    if (p >= WP_TOT) return;
    const float* W; int N, Kt; int q = p;
    if (p < WP_PROJ)      { W = qkv_w;  N = 576; Kt = 6;  }
    else if (p < WP_MLP1) { W = proj_w; N = 192; Kt = 6;  q -= WP_PROJ; }
    else if (p < WP_MLP2) { W = mlp_w1; N = 768; Kt = 6;  q -= WP_MLP1; }
    else                  { W = mlp_w2; N = 192; Kt = 24; q -= WP_MLP2; }
    int j    = (q & 3) * 2;
    int lane = (q >> 2) & 63;
    int kt   = (q >> 8) % Kt;
    int nt   = (q >> 8) / Kt;
    int k = kt * 32 + (lane >> 4) * 8 + j;
    int n = nt * 16 + (lane & 15);
    union { bf16_t h[2]; unsigned u; } pk;
    pk.h[0] = (bf16_t)W[k * N + n];
    pk.h[1] = (bf16_t)W[(k + 1) * N + n];
    *(unsigned*)(dst + p * 2) = pk.u;
}

// ---------------- main fused kernel ----------------
// EXACT R1 structure (417 us anchor) with ONLY erff-gelu -> fast_gelu swapped.
// LDS arena (46080 B). bf16 activation rows: 192 cols in 400-B rows.
//  aA   [0,19200)      bf16 [48][200]  LN1 out / QKV A (compact 48 rows)
//  wavebufs 19200+wv*4480 (4480 B/wave, attention phase only):
//      Qb [24][40] @0      (Pb aliases Qb)
//      Kb [24][40] @1920   (Vt [32][40] aliases Kb; V scattered AFTER S-MFMA reads K)
//  aO   [0,19200)      bf16 [48][200]  attn out / proj A (aliases aA)
//  aH2  [0,19200)      bf16 [48][200]  LN2 out / MLP1 A (aliases aO, dead)
//  xw2b [19200,38400)  bf16 [48][200]  residual1 copy (LN2 input only; f32 copy in regs)
//  aHid [19200,38400)  bf16 [48][200]  gelu chunk / MLP2 A (aliases xw2b, dead after LN2)
// Residency: register-capped at 2 blocks/CU (acc[3][6]=72 unified regs + ~84 VGPR).
// NOTE: kt loops deliberately NOT pragma-unrolled; merged/pipelined MLP variants
// regressed (R2: 555us, R3: 436us vs this structure's 417us) — compiler's own
// schedule of the simple form wins.
__global__ __launch_bounds__(384, 3)
void pangu_main(const float* __restrict__ x,
                const float* __restrict__ ln1_g, const float* __restrict__ ln1_b,
                const float* __restrict__ qkv_b,
                const float* __restrict__ bias_table,
                const float* __restrict__ proj_b,
                const float* __restrict__ ln2_g, const float* __restrict__ ln2_b,
                const float* __restrict__ mlp_b1, const float* __restrict__ mlp_b2,
                const int* __restrict__ rel_index,
                const bf16_t* __restrict__ wf,
                float* __restrict__ out)
{
    __shared__ __align__(16) unsigned char arena[46080];
    __shared__ int   sRowOff[48];
    __shared__ float sMu[48], sRs[48];

    unsigned char* aAb   = arena;
    unsigned char* aOb   = arena;                 // alias aA (post-QKV barrier)
    unsigned char* aH2b  = arena;                 // alias aO (dead)
    unsigned char* xw2b  = arena + 19200;
    unsigned char* aHidb = arena + 19200;         // alias xw2 (dead after LN2 normalize)
    bf16_t* aO   = (bf16_t*)aOb;
    bf16_t* aHid = (bf16_t*)aHidb;
    bf16_t* xw2h = (bf16_t*)xw2b;

    const int t    = threadIdx.x;
    const int lane = t & 63;
    const int wv   = t >> 6;          // 0..5 (wave id == head id)
    const int quad = lane >> 4;
    const int l15  = lane & 15;
    const int q4   = quad * 4;

    // ---- row offsets of the 48 tokens (2 windows) ----
    if (t < 48) {
        int win = t / 24, tok = t % 24;
        int W = blockIdx.x * 2 + win;
        int id_ = W % 7;  int r1 = W / 7;
        int iw_ = r1 % 16; int r2 = r1 / 16;
        int ih_ = r2 % 24; int b  = r2 / 24;
        int i = tok / 12, j = (tok % 12) / 2, k = tok % 2;
        sRowOff[t] = (((b * 48 + ih_ * 2 + i) * 96 + iw_ * 6 + j) * 14 + id_ * 2 + k) * 192;
    }
    __syncthreads();

    // ---- LN1 entirely in registers: 8 threads/row, 24 f32 each ----
    {
        int r48 = t >> 3, l = t & 7;
        const float* xr = x + sRowOff[r48];
        float4 v[6];
        #pragma unroll
        for (int s = 0; s < 6; ++s) v[s] = *(const float4*)(xr + l * 4 + s * 32);
        float sm = 0.f, s2 = 0.f;
        #pragma unroll
        for (int s = 0; s < 6; ++s) {
            sm += v[s].x + v[s].y + v[s].z + v[s].w;
            s2 += v[s].x * v[s].x + v[s].y * v[s].y + v[s].z * v[s].z + v[s].w * v[s].w;
        }
        sm += __shfl_xor(sm, 1); s2 += __shfl_xor(s2, 1);
        sm += __shfl_xor(sm, 2); s2 += __shfl_xor(s2, 2);
        sm += __shfl_xor(sm, 4); s2 += __shfl_xor(s2, 4);
        float mu = sm * (1.f / 192.f);
        float var = s2 * (1.f / 192.f) - mu * mu;
        float rs = rsqrtf(var + 1e-5f);
        int row = r48;   // compact 48-row layout
        #pragma unroll
        for (int s = 0; s < 6; ++s) {
            int c = l * 4 + s * 32;
            union { bf16_t h[4]; uint2 u; } pk;
            pk.h[0] = (bf16_t)((v[s].x - mu) * rs * ln1_g[c]     + ln1_b[c]);
            pk.h[1] = (bf16_t)((v[s].y - mu) * rs * ln1_g[c + 1] + ln1_b[c + 1]);
            pk.h[2] = (bf16_t)((v[s].z - mu) * rs * ln1_g[c + 2] + ln1_b[c + 2]);
            pk.h[3] = (bf16_t)((v[s].w - mu) * rs * ln1_g[c + 3] + ln1_b[c + 3]);
            *(uint2*)(aAb + row * 400 + c * 2) = pk.u;
        }
    }
    __syncthreads();

    // ================= QKV GEMM + attention =================
    {
        const int h = wv;
        unsigned char* wb = arena + 19200 + wv * 4480;
        bf16_t* Qb = (bf16_t*)wb;                 // Pb aliases Qb
        bf16_t* Kb = (bf16_t*)(wb + 1920);        // Vt aliases Kb
        bf16_t* Vt = (bf16_t*)(wb + 1920);
        bf16_t* Pb = (bf16_t*)wb;

        // QKV mini-GEMM: M tiles 0..2 (48 compact rows), N = head's q/k/v (6 ntiles), K = 6 ktiles
        f32x4 acc[3][6];
        {
            float bq[6];
            const int ntg[6] = {2*h, 2*h+1, 12+2*h, 13+2*h, 24+2*h, 25+2*h};
            #pragma unroll
            for (int n = 0; n < 6; ++n) bq[n] = qkv_b[ntg[n] * 16 + l15];
            #pragma unroll
            for (int m = 0; m < 3; ++m)
                #pragma unroll
                for (int n = 0; n < 6; ++n)
                    acc[m][n] = (f32x4){bq[n], bq[n], bq[n], bq[n]};
            for (int kt = 0; kt < 6; ++kt) {
                bf16x8 af[3];
                #pragma unroll
                for (int m = 0; m < 3; ++m)
                    af[m] = *(const bf16x8*)(aAb + (l15 + m * 16) * 400 + kt * 64 + quad * 16);
                #pragma unroll
                for (int n = 0; n < 6; ++n) {
                    bf16x8 bfr = *(const bf16x8*)(wf + WF_QKV + ((ntg[n] * 6 + kt) * 64 + lane) * 8);
                    #pragma unroll
                    for (int m = 0; m < 3; ++m)
                        acc[m][n] = __builtin_amdgcn_mfma_f32_16x16x32_bf16(af[m], bfr, acc[m][n], 0, 0, 0);
                }
            }
        }
        __syncthreads();   // all waves done reading aA; aO (alias) written below

        const float scale = 0.1767766952966369f;  // 1/sqrt(32)
        #pragma unroll
        for (int win = 0; win < 2; ++win) {
            // scatter Q (scaled) and K only (V deferred; Vt aliases Kb)
            #pragma unroll
            for (int m = 0; m < 3; ++m)
                #pragma unroll
                for (int i = 0; i < 4; ++i) {
                    int tok = m * 16 + q4 + i - win * 24;
                    if (tok >= 0 && tok < 24) {
                        #pragma unroll
                        for (int nt = 0; nt < 2; ++nt) {
                            int d = nt * 16 + l15;
                            Qb[tok * 40 + d] = (bf16_t)(acc[m][nt][i] * scale);
                            Kb[tok * 40 + d] = (bf16_t)(acc[m][2+nt][i]);
                        }
                    }
                }
            // S = Qs.K^T + bias  (bias gathered as C-init)
            f32x4 sacc[2][2];
            #pragma unroll
            for (int mt = 0; mt < 2; ++mt)
                #pragma unroll
                for (int nt = 0; nt < 2; ++nt)
                    #pragma unroll
                    for (int i = 0; i < 4; ++i) {
                        int n = mt * 16 + q4 + i; if (n > 23) n = 23;
                        int m = nt * 16 + l15;    if (m > 23) m = 23;
                        sacc[mt][nt][i] = bias_table[rel_index[n * 24 + m] * 6 + h];
                    }
            #pragma unroll
            for (int nt = 0; nt < 2; ++nt) {
                bf16x8 kf = *(const bf16x8*)((unsigned char*)Kb + (l15 + nt * 16) * 80 + quad * 16);
                #pragma unroll
                for (int mt = 0; mt < 2; ++mt) {
                    bf16x8 qf = *(const bf16x8*)((unsigned char*)Qb + (l15 + mt * 16) * 80 + quad * 16);
                    sacc[mt][nt] = __builtin_amdgcn_mfma_f32_16x16x32_bf16(qf, kf, sacc[mt][nt], 0, 0, 0);
                }
            }
            // V scatter now (Kb dead): real toks + zero pads 24..31
            #pragma unroll
            for (int m = 0; m < 3; ++m)
                #pragma unroll
                for (int i = 0; i < 4; ++i) {
                    int tok = m * 16 + q4 + i - win * 24;
                    if (tok >= 0 && tok < 24) {
                        #pragma unroll
                        for (int nt = 0; nt < 2; ++nt)
                            Vt[(nt * 16 + l15) * 40 + tok] = (bf16_t)(acc[m][4+nt][i]);
                    }
                }
            {
                int d = lane >> 1, half = lane & 1;
                *(uint2*)((unsigned char*)Vt + d * 80 + 48 + half * 8) = make_uint2(0u, 0u);
            }
            // in-register softmax over cols 0..23 (row lives in 16 lanes of one quad)
            #pragma unroll
            for (int mt = 0; mt < 2; ++mt)
                #pragma unroll
                for (int i = 0; i < 4; ++i) {
                    float s0 = sacc[mt][0][i];
                    float s1m = (l15 < 8) ? sacc[mt][1][i] : -1e30f;
                    float mx = fmaxf(s0, s1m);
                    mx = fmaxf(mx, __shfl_xor(mx, 1));
                    mx = fmaxf(mx, __shfl_xor(mx, 2));
                    mx = fmaxf(mx, __shfl_xor(mx, 4));
                    mx = fmaxf(mx, __shfl_xor(mx, 8));
                    float e0 = __expf(s0 - mx);
                    float e1 = (l15 < 8) ? __expf(sacc[mt][1][i] - mx) : 0.f;
                    float sum = e0 + e1;
                    sum += __shfl_xor(sum, 1);
                    sum += __shfl_xor(sum, 2);
                    sum += __shfl_xor(sum, 4);
                    sum += __shfl_xor(sum, 8);
                    float inv = 1.f / sum;
                    sacc[mt][0][i] = e0 * inv;
                    sacc[mt][1][i] = e1 * inv;   // 0 for cols 24..31
                }
            // P -> LDS (A-operand layout; aliases Qb, Q dead)
            #pragma unroll
            for (int mt = 0; mt < 2; ++mt)
                #pragma unroll
                for (int i = 0; i < 4; ++i) {
                    int r = mt * 16 + q4 + i;
                    if (r < 24) {
                        Pb[r * 40 + l15]      = (bf16_t)sacc[mt][0][i];
                        Pb[r * 40 + 16 + l15] = (bf16_t)sacc[mt][1][i];
                    }
                }
            // O = P.V
            f32x4 oacc[2][2];
            #pragma unroll
            for (int mt = 0; mt < 2; ++mt)
                #pragma unroll
                for (int nt = 0; nt < 2; ++nt)
                    oacc[mt][nt] = (f32x4){0.f, 0.f, 0.f, 0.f};
            #pragma unroll
            for (int nt = 0; nt < 2; ++nt) {
                bf16x8 vf = *(const bf16x8*)((unsigned char*)Vt + (l15 + nt * 16) * 80 + quad * 16);
                #pragma unroll
                for (int mt = 0; mt < 2; ++mt) {
                    bf16x8 pf = *(const bf16x8*)((unsigned char*)Pb + (l15 + mt * 16) * 80 + quad * 16);
                    oacc[mt][nt] = __builtin_amdgcn_mfma_f32_16x16x32_bf16(pf, vf, oacc[mt][nt], 0, 0, 0);
                }
            }
            // O -> aO (48-row compact, proj A layout)
            #pragma unroll
            for (int mt = 0; mt < 2; ++mt)
                #pragma unroll
                for (int i = 0; i < 4; ++i) {
                    int tok = mt * 16 + q4 + i;
                    if (tok < 24) {
                        int r = win * 24 + tok;
                        #pragma unroll
                        for (int nt = 0; nt < 2; ++nt)
                            aO[r * 200 + h * 32 + nt * 16 + l15] = (bf16_t)oacc[mt][nt][i];
                    }
                }
        } // win
    }
    __syncthreads();

    // ================= proj GEMM (M=48, 2 ntiles/wave) + residual =================
    float rxw[3][2][4];   // f32 residual carried in registers to the final store
    {
        f32x4 pacc[3][2];
        #pragma unroll
        for (int m = 0; m < 3; ++m)
            #pragma unroll
            for (int n = 0; n < 2; ++n) pacc[m][n] = (f32x4){0.f, 0.f, 0.f, 0.f};
        for (int kt = 0; kt < 6; ++kt) {
            bf16x8 af[3];
            #pragma unroll
            for (int m = 0; m < 3; ++m)
                af[m] = *(const bf16x8*)(aOb + (l15 + m * 16) * 400 + kt * 64 + quad * 16);
            #pragma unroll
            for (int n = 0; n < 2; ++n) {
                int NT = wv * 2 + n;
                bf16x8 bfr = *(const bf16x8*)(wf + WF_PROJ + ((NT * 6 + kt) * 64 + lane) * 8);
                #pragma unroll
                for (int m = 0; m < 3; ++m)
                    pacc[m][n] = __builtin_amdgcn_mfma_f32_16x16x32_bf16(af[m], bfr, pacc[m][n], 0, 0, 0);
            }
        }
        __syncthreads();   // all aO reads done before xw2b writes
        #pragma unroll
        for (int n = 0; n < 2; ++n) {
            int c = (wv * 2 + n) * 16 + l15;
            float pb = proj_b[c];
            #pragma unroll
            for (int m = 0; m < 3; ++m)
                #pragma unroll
                for (int i = 0; i < 4; ++i) {
                    int r = m * 16 + q4 + i;
                    float val = x[sRowOff[r] + c] + pb + pacc[m][n][i];
                    rxw[m][n][i] = val;
                    xw2h[r * 200 + c] = (bf16_t)val;
                }
        }
    }
    __syncthreads();

    // ---- LN2 stats from bf16 xw2 copy ----
    {
        int r = t >> 3, l = t & 7;
        float sm = 0.f, s2 = 0.f;
        #pragma unroll
        for (int s = 0; s < 6; ++s) {
            union { bf16_t h[4]; uint2 u; } pk;
            pk.u = *(const uint2*)(xw2b + r * 400 + l * 8 + s * 64);
            #pragma unroll
            for (int z = 0; z < 4; ++z) { float v = (float)pk.h[z]; sm += v; s2 += v * v; }
        }
        sm += __shfl_xor(sm, 1); s2 += __shfl_xor(s2, 1);
        sm += __shfl_xor(sm, 2); s2 += __shfl_xor(s2, 2);
        sm += __shfl_xor(sm, 4); s2 += __shfl_xor(s2, 4);
        if (l == 0) {
            float mu = sm * (1.f / 192.f);
            float var = s2 * (1.f / 192.f) - mu * mu;
            sMu[r] = mu; sRs[r] = rsqrtf(var + 1e-5f);
        }
    }
    __syncthreads();
    // ---- LN2 normalize -> aH2 ----
    for (int p = t; p < 4608; p += 384) {
        int r = p / 96, c2 = p % 96, c = c2 * 2;
        float mu = sMu[r], rs = sRs[r];
        union { bf16_t h[2]; unsigned u; } in, pk;
        in.u = *(const unsigned*)(xw2b + r * 400 + c2 * 4);
        pk.h[0] = (bf16_t)(((float)in.h[0] - mu) * rs * ln2_g[c]     + ln2_b[c]);
        pk.h[1] = (bf16_t)(((float)in.h[1] - mu) * rs * ln2_g[c + 1] + ln2_b[c + 1]);
        *(unsigned*)(aH2b + r * 400 + c2 * 4) = pk.u;
    }
    __syncthreads();

    // ================= MLP: 4 chunks of 192 hidden cols =================
    f32x4 acc2[3][2];
    #pragma unroll
    for (int m = 0; m < 3; ++m)
        #pragma unroll
        for (int n = 0; n < 2; ++n) {
            float b2 = mlp_b2[(wv * 2 + n) * 16 + l15];
            acc2[m][n] = (f32x4){b2, b2, b2, b2};
        }
    for (int ch = 0; ch < 4; ++ch) {
        f32x4 a1[3][2];
        #pragma unroll
        for (int m = 0; m < 3; ++m)
            #pragma unroll
            for (int n = 0; n < 2; ++n) {
                float b1 = mlp_b1[ch * 192 + (wv * 2 + n) * 16 + l15];
                a1[m][n] = (f32x4){b1, b1, b1, b1};
            }
        for (int kt = 0; kt < 6; ++kt) {
            bf16x8 af[3];
            #pragma unroll
            for (int m = 0; m < 3; ++m)
                af[m] = *(const bf16x8*)(aH2b + (l15 + m * 16) * 400 + kt * 64 + quad * 16);
            #pragma unroll
            for (int n = 0; n < 2; ++n) {
                int NT = ch * 12 + wv * 2 + n;
                bf16x8 bfr = *(const bf16x8*)(wf + WF_MLP1 + ((NT * 6 + kt) * 64 + lane) * 8);
                #pragma unroll
                for (int m = 0; m < 3; ++m)
                    a1[m][n] = __builtin_amdgcn_mfma_f32_16x16x32_bf16(af[m], bfr, a1[m][n], 0, 0, 0);
            }
        }
        // fast gelu -> aHid
        #pragma unroll
        for (int n = 0; n < 2; ++n) {
            int c = (wv * 2 + n) * 16 + l15;
            #pragma unroll
            for (int m = 0; m < 3; ++m)
                #pragma unroll
                for (int i = 0; i < 4; ++i) {
                    int r = m * 16 + q4 + i;
                    aHid[r * 200 + c] = (bf16_t)fast_gelu(a1[m][n][i]);
                }
        }
        __syncthreads();
        // MLP2 partial over this K chunk
        for (int kt = 0; kt < 6; ++kt) {
            bf16x8 af[3];
            #pragma unroll
            for (int m = 0; m < 3; ++m)
                af[m] = *(const bf16x8*)(aHidb + (l15 + m * 16) * 400 + kt * 64 + quad * 16);
            #pragma unroll
            for (int n = 0; n < 2; ++n) {
                int NT = wv * 2 + n;
                int ktg = ch * 6 + kt;
                bf16x8 bfr = *(const bf16x8*)(wf + WF_MLP2 + ((NT * 24 + ktg) * 64 + lane) * 8);
                #pragma unroll
                for (int m = 0; m < 3; ++m)
                    acc2[m][n] = __builtin_amdgcn_mfma_f32_16x16x32_bf16(af[m], bfr, acc2[m][n], 0, 0, 0);
            }
        }
        __syncthreads();
    }

    // ---- final: out = xw2(regs) + mlp ----
    #pragma unroll
    for (int n = 0; n < 2; ++n) {
        int c = (wv * 2 + n) * 16 + l15;
        #pragma unroll
        for (int m = 0; m < 3; ++m)
            #pragma unroll
            for (int i = 0; i < 4; ++i) {
                int r = m * 16 + q4 + i;
                out[sRowOff[r] + c] = rxw[m][n][i] + acc2[m][n][i];
            }
    }
}

extern "C" void kernel_launch(void* const* d_in, const int* in_sizes, int n_in,
                              void* d_out, int out_size, void* d_ws, size_t ws_size,
                              hipStream_t stream) {
    const float* x          = (const float*)d_in[0];
    const float* ln1_g      = (const float*)d_in[1];
    const float* ln1_b      = (const float*)d_in[2];
    const float* qkv_w      = (const float*)d_in[3];
    const float* qkv_b      = (const float*)d_in[4];
    const float* bias_table = (const float*)d_in[5];
    const float* proj_w     = (const float*)d_in[6];
    const float* proj_b     = (const float*)d_in[7];
    const float* ln2_g      = (const float*)d_in[8];
    const float* ln2_b      = (const float*)d_in[9];
    const float* mlp_w1     = (const float*)d_in[10];
    const float* mlp_b1     = (const float*)d_in[11];
    const float* mlp_w2     = (const float*)d_in[12];
    const float* mlp_b2     = (const float*)d_in[13];
    const int*   rel_index  = (const int*)d_in[14];
    float* out = (float*)d_out;
    bf16_t* wsb = (bf16_t*)d_ws;

    preproc_all<<<(WP_TOT + 255) / 256, 256, 0, stream>>>(qkv_w, proj_w, mlp_w1, mlp_w2, wsb);

    pangu_main<<<NBLK, 384, 0, stream>>>(
        x, ln1_g, ln1_b, qkv_b, bias_table, proj_b, ln2_g, ln2_b,
        mlp_b1, mlp_b2, rel_index, wsb, out);
}

// Round 6
// 541.612 us; speedup vs baseline: 1.2044x; 1.2044x over previous
//
#include <hip/hip_runtime.h>
#include <hip/hip_bf16.h>
#include <math.h>

typedef __bf16 bf16_t;
typedef __bf16 bf16x8 __attribute__((ext_vector_type(8)));
typedef float  f32x4  __attribute__((ext_vector_type(4)));

#define NBLK 2688          // 5376 windows / 2 per block
// pair offsets (1 pair = 2 bf16) of pre-swizzled weights inside d_ws
#define WP_QKV  0
#define WP_PROJ 55296
#define WP_MLP1 73728
#define WP_MLP2 147456
#define WP_TOT  221184
// bf16 element offsets
#define WF_QKV  0
#define WF_PROJ 110592
#define WF_MLP1 147456
#define WF_MLP2 294912

// ---------------- merged weight pre-swizzle: W[K][N] f32 -> B-fragment bf16 ----------------
// frag(nt,kt): dst[((nt*Kt + kt)*64 + lane)*8 + j] = W[kt*32 + (lane>>4)*8 + j][nt*16 + (lane&15)]
__global__ void preproc_all(const float* __restrict__ qkv_w, const float* __restrict__ proj_w,
                            const float* __restrict__ mlp_w1, const float* __restrict__ mlp_w2,
                            bf16_t* __restrict__ dst) {
    int p = blockIdx.x * 256 + threadIdx.x;
    if (p >= WP_TOT) return;
    const float* W; int N, Kt; int q = p;
    if (p < WP_PROJ)      { W = qkv_w;  N = 576; Kt = 6;  }
    else if (p < WP_MLP1) { W = proj_w; N = 192; Kt = 6;  q -= WP_PROJ; }
    else if (p < WP_MLP2) { W = mlp_w1; N = 768; Kt = 6;  q -= WP_MLP1; }
    else                  { W = mlp_w2; N = 192; Kt = 24; q -= WP_MLP2; }
    int j    = (q & 3) * 2;
    int lane = (q >> 2) & 63;
    int kt   = (q >> 8) % Kt;
    int nt   = (q >> 8) / Kt;
    int k = kt * 32 + (lane >> 4) * 8 + j;
    int n = nt * 16 + (lane & 15);
    union { bf16_t h[2]; unsigned u; } pk;
    pk.h[0] = (bf16_t)W[k * N + n];
    pk.h[1] = (bf16_t)W[(k + 1) * N + n];
    *(unsigned*)(dst + p * 2) = pk.u;
}

// ---------------- main fused kernel ----------------
// R1 structure (417us anchor, erff gelu) with the QKV/attention section restructured
// to cut the attention-phase register peak (was ~188 total regs -> 1 block/CU).
// QKV is split: pass1 = K,V ntiles (acc[3][4]), scattered to LDS for BOTH windows
// immediately; pass2 = Q ntiles (acc[3][2]) kept live through the win loop.
// Attention live set drops 104 AGPR -> ~56 AGPR; total ~140 <= 170 -> 3 waves/SIMD
// -> 2 blocks/CU resident (occupancy was the binding constraint; MFMA busy is a
// constant 49us every round = ideal issue time).
//
// LDS arena (75264 B). bf16 activation rows: 192 cols in 400-B rows.
//  aA   [0,19200)      bf16 [48][200]  LN1 out / QKV A (compact 48 rows)
//  wavebufs 19200+wv*9344 (9344 B/wave, attention phase only):
//      Qb  [24][40] @0     per-window Q (Pb aliases Qb; pad-row reads spill = discarded)
//      Kb2 [48][40] @1920  K for BOTH windows (win1 nt1 reads spill into Vt = masked)
//      Vt  [32][56] @5760  V^T for BOTH windows (+8 pad cols, zeroed)
//  aO   [0,19200)      bf16 [48][200]  attn out / proj A (aliases aA)
//  aH2  [0,19200)      bf16 [48][200]  LN2 out / MLP1 A (aliases aO, dead)
//  xw2b [19200,38400)  bf16 [48][200]  residual1 copy (wavebufs dead by then)
//  aHid [19200,38400)  bf16 [48][200]  gelu chunk / MLP2 A (aliases xw2b)
// 75264+576 statics -> ~75840/block -> 2 blocks/CU (151.7KB <= 160KB).
// NOTE: erff gelu kept (fast_gelu REGRESSED: R5 537us vs 417 — ROCm erff is a cheap
// polynomial; exp+rcp chain is more expensive). kt loops NOT pragma-unrolled (R2).
__global__ __launch_bounds__(384, 3)
void pangu_main(const float* __restrict__ x,
                const float* __restrict__ ln1_g, const float* __restrict__ ln1_b,
                const float* __restrict__ qkv_b,
                const float* __restrict__ bias_table,
                const float* __restrict__ proj_b,
                const float* __restrict__ ln2_g, const float* __restrict__ ln2_b,
                const float* __restrict__ mlp_b1, const float* __restrict__ mlp_b2,
                const int* __restrict__ rel_index,
                const bf16_t* __restrict__ wf,
                float* __restrict__ out)
{
    __shared__ __align__(16) unsigned char arena[75264];
    __shared__ int   sRowOff[48];
    __shared__ float sMu[48], sRs[48];

    unsigned char* aAb   = arena;
    unsigned char* aOb   = arena;                 // alias aA (post-QKV barrier)
    unsigned char* aH2b  = arena;                 // alias aO (dead)
    unsigned char* xw2b  = arena + 19200;
    unsigned char* aHidb = arena + 19200;         // alias xw2 (dead after LN2 normalize)
    bf16_t* aO   = (bf16_t*)aOb;
    bf16_t* aHid = (bf16_t*)aHidb;
    bf16_t* xw2h = (bf16_t*)xw2b;

    const int t    = threadIdx.x;
    const int lane = t & 63;
    const int wv   = t >> 6;          // 0..5 (wave id == head id)
    const int quad = lane >> 4;
    const int l15  = lane & 15;
    const int q4   = quad * 4;

    // ---- row offsets of the 48 tokens (2 windows) ----
    if (t < 48) {
        int win = t / 24, tok = t % 24;
        int W = blockIdx.x * 2 + win;
        int id_ = W % 7;  int r1 = W / 7;
        int iw_ = r1 % 16; int r2 = r1 / 16;
        int ih_ = r2 % 24; int b  = r2 / 24;
        int i = tok / 12, j = (tok % 12) / 2, k = tok % 2;
        sRowOff[t] = (((b * 48 + ih_ * 2 + i) * 96 + iw_ * 6 + j) * 14 + id_ * 2 + k) * 192;
    }
    __syncthreads();

    // ---- LN1 entirely in registers: 8 threads/row, 24 f32 each ----
    {
        int r48 = t >> 3, l = t & 7;
        const float* xr = x + sRowOff[r48];
        float4 v[6];
        #pragma unroll
        for (int s = 0; s < 6; ++s) v[s] = *(const float4*)(xr + l * 4 + s * 32);
        float sm = 0.f, s2 = 0.f;
        #pragma unroll
        for (int s = 0; s < 6; ++s) {
            sm += v[s].x + v[s].y + v[s].z + v[s].w;
            s2 += v[s].x * v[s].x + v[s].y * v[s].y + v[s].z * v[s].z + v[s].w * v[s].w;
        }
        sm += __shfl_xor(sm, 1); s2 += __shfl_xor(s2, 1);
        sm += __shfl_xor(sm, 2); s2 += __shfl_xor(s2, 2);
        sm += __shfl_xor(sm, 4); s2 += __shfl_xor(s2, 4);
        float mu = sm * (1.f / 192.f);
        float var = s2 * (1.f / 192.f) - mu * mu;
        float rs = rsqrtf(var + 1e-5f);
        int row = r48;   // compact 48-row layout
        #pragma unroll
        for (int s = 0; s < 6; ++s) {
            int c = l * 4 + s * 32;
            union { bf16_t h[4]; uint2 u; } pk;
            pk.h[0] = (bf16_t)((v[s].x - mu) * rs * ln1_g[c]     + ln1_b[c]);
            pk.h[1] = (bf16_t)((v[s].y - mu) * rs * ln1_g[c + 1] + ln1_b[c + 1]);
            pk.h[2] = (bf16_t)((v[s].z - mu) * rs * ln1_g[c + 2] + ln1_b[c + 2]);
            pk.h[3] = (bf16_t)((v[s].w - mu) * rs * ln1_g[c + 3] + ln1_b[c + 3]);
            *(uint2*)(aAb + row * 400 + c * 2) = pk.u;
        }
    }
    __syncthreads();

    // ================= QKV GEMM (2 passes) + attention =================
    {
        const int h = wv;
        unsigned char* wb = arena + 19200 + wv * 9344;
        bf16_t* Qb  = (bf16_t*)wb;                 // [24][40] per-win; Pb aliases
        bf16_t* Kb2 = (bf16_t*)(wb + 1920);        // [48][40] both windows
        bf16_t* Vt  = (bf16_t*)(wb + 5760);        // [32][56] both windows (+pad cols)
        bf16_t* Pb  = (bf16_t*)wb;

        // ---- pass 1: K,V ntiles (4 per head), acc[3][4] ----
        {
            f32x4 acc[3][4];
            const int ntg[4] = {12+2*h, 13+2*h, 24+2*h, 25+2*h};
            float bq[4];
            #pragma unroll
            for (int n = 0; n < 4; ++n) bq[n] = qkv_b[ntg[n] * 16 + l15];
            #pragma unroll
            for (int m = 0; m < 3; ++m)
                #pragma unroll
                for (int n = 0; n < 4; ++n)
                    acc[m][n] = (f32x4){bq[n], bq[n], bq[n], bq[n]};
            for (int kt = 0; kt < 6; ++kt) {
                bf16x8 af[3];
                #pragma unroll
                for (int m = 0; m < 3; ++m)
                    af[m] = *(const bf16x8*)(aAb + (l15 + m * 16) * 400 + kt * 64 + quad * 16);
                #pragma unroll
                for (int n = 0; n < 4; ++n) {
                    bf16x8 bfr = *(const bf16x8*)(wf + WF_QKV + ((ntg[n] * 6 + kt) * 64 + lane) * 8);
                    #pragma unroll
                    for (int m = 0; m < 3; ++m)
                        acc[m][n] = __builtin_amdgcn_mfma_f32_16x16x32_bf16(af[m], bfr, acc[m][n], 0, 0, 0);
                }
            }
            // scatter K (both wins) and V^T (both wins); wave-private, no barrier needed
            #pragma unroll
            for (int m = 0; m < 3; ++m)
                #pragma unroll
                for (int i = 0; i < 4; ++i) {
                    int row = m * 16 + q4 + i;   // 0..47 global token
                    #pragma unroll
                    for (int nt = 0; nt < 2; ++nt) {
                        int d = nt * 16 + l15;
                        Kb2[row * 40 + d] = (bf16_t)(acc[m][nt][i]);
                        Vt[d * 56 + row]  = (bf16_t)(acc[m][2+nt][i]);
                    }
                }
            // zero Vt pad cols 48..55 (read by win1's PV k-range; P=0 there but avoid NaN)
            {
                int d = lane >> 1, half = lane & 1;
                *(uint2*)((unsigned char*)Vt + d * 112 + 96 + half * 8) = make_uint2(0u, 0u);
            }
        }

        // ---- pass 2: Q ntiles (2 per head), qacc[3][2] stays live through win loop ----
        f32x4 qacc[3][2];
        {
            const int ntg[2] = {2*h, 2*h+1};
            float bq[2];
            #pragma unroll
            for (int n = 0; n < 2; ++n) bq[n] = qkv_b[ntg[n] * 16 + l15];
            #pragma unroll
            for (int m = 0; m < 3; ++m)
                #pragma unroll
                for (int n = 0; n < 2; ++n)
                    qacc[m][n] = (f32x4){bq[n], bq[n], bq[n], bq[n]};
            for (int kt = 0; kt < 6; ++kt) {
                bf16x8 af[3];
                #pragma unroll
                for (int m = 0; m < 3; ++m)
                    af[m] = *(const bf16x8*)(aAb + (l15 + m * 16) * 400 + kt * 64 + quad * 16);
                #pragma unroll
                for (int n = 0; n < 2; ++n) {
                    bf16x8 bfr = *(const bf16x8*)(wf + WF_QKV + ((ntg[n] * 6 + kt) * 64 + lane) * 8);
                    #pragma unroll
                    for (int m = 0; m < 3; ++m)
                        qacc[m][n] = __builtin_amdgcn_mfma_f32_16x16x32_bf16(af[m], bfr, qacc[m][n], 0, 0, 0);
                }
            }
        }
        __syncthreads();   // all waves done reading aA; aO (alias) written below

        const float scale = 0.1767766952966369f;  // 1/sqrt(32)
        #pragma unroll
        for (int win = 0; win < 2; ++win) {
            // scatter Q (scaled) for this window from qacc
            #pragma unroll
            for (int m = 0; m < 3; ++m)
                #pragma unroll
                for (int i = 0; i < 4; ++i) {
                    int tok = m * 16 + q4 + i - win * 24;
                    if (tok >= 0 && tok < 24) {
                        #pragma unroll
                        for (int nt = 0; nt < 2; ++nt)
                            Qb[tok * 40 + nt * 16 + l15] = (bf16_t)(qacc[m][nt][i] * scale);
                    }
                }
            // S = Qs.K^T + bias  (bias gathered as C-init)
            f32x4 sacc[2][2];
            #pragma unroll
            for (int mt = 0; mt < 2; ++mt)
                #pragma unroll
                for (int nt = 0; nt < 2; ++nt)
                    #pragma unroll
                    for (int i = 0; i < 4; ++i) {
                        int n = mt * 16 + q4 + i; if (n > 23) n = 23;
                        int m = nt * 16 + l15;    if (m > 23) m = 23;
                        sacc[mt][nt][i] = bias_table[rel_index[n * 24 + m] * 6 + h];
                    }
            #pragma unroll
            for (int nt = 0; nt < 2; ++nt) {
                bf16x8 kf = *(const bf16x8*)((unsigned char*)Kb2 + (win * 24 + l15 + nt * 16) * 80 + quad * 16);
                #pragma unroll
                for (int mt = 0; mt < 2; ++mt) {
                    bf16x8 qf = *(const bf16x8*)((unsigned char*)Qb + (l15 + mt * 16) * 80 + quad * 16);
                    sacc[mt][nt] = __builtin_amdgcn_mfma_f32_16x16x32_bf16(qf, kf, sacc[mt][nt], 0, 0, 0);
                }
            }
            // in-register softmax over cols 0..23 (row lives in 16 lanes of one quad)
            #pragma unroll
            for (int mt = 0; mt < 2; ++mt)
                #pragma unroll
                for (int i = 0; i < 4; ++i) {
                    float s0 = sacc[mt][0][i];
                    float s1m = (l15 < 8) ? sacc[mt][1][i] : -1e30f;
                    float mx = fmaxf(s0, s1m);
                    mx = fmaxf(mx, __shfl_xor(mx, 1));
                    mx = fmaxf(mx, __shfl_xor(mx, 2));
                    mx = fmaxf(mx, __shfl_xor(mx, 4));
                    mx = fmaxf(mx, __shfl_xor(mx, 8));
                    float e0 = __expf(s0 - mx);
                    float e1 = (l15 < 8) ? __expf(sacc[mt][1][i] - mx) : 0.f;
                    float sum = e0 + e1;
                    sum += __shfl_xor(sum, 1);
                    sum += __shfl_xor(sum, 2);
                    sum += __shfl_xor(sum, 4);
                    sum += __shfl_xor(sum, 8);
                    float inv = 1.f / sum;
                    sacc[mt][0][i] = e0 * inv;
                    sacc[mt][1][i] = e1 * inv;   // 0 for cols 24..31
                }
            // P -> LDS (A-operand layout; aliases Qb, Q dead for this window)
            #pragma unroll
            for (int mt = 0; mt < 2; ++mt)
                #pragma unroll
                for (int i = 0; i < 4; ++i) {
                    int r = mt * 16 + q4 + i;
                    if (r < 24) {
                        Pb[r * 40 + l15]      = (bf16_t)sacc[mt][0][i];
                        Pb[r * 40 + 16 + l15] = (bf16_t)sacc[mt][1][i];
                    }
                }
            // O = P.V  (Vt cols win*24 .. win*24+31; P=0 beyond 24 real toks)
            f32x4 oacc[2][2];
            #pragma unroll
            for (int mt = 0; mt < 2; ++mt)
                #pragma unroll
                for (int nt = 0; nt < 2; ++nt)
                    oacc[mt][nt] = (f32x4){0.f, 0.f, 0.f, 0.f};
            #pragma unroll
            for (int nt = 0; nt < 2; ++nt) {
                bf16x8 vf = *(const bf16x8*)((unsigned char*)Vt + (l15 + nt * 16) * 112 + win * 48 + quad * 16);
                #pragma unroll
                for (int mt = 0; mt < 2; ++mt) {
                    bf16x8 pf = *(const bf16x8*)((unsigned char*)Pb + (l15 + mt * 16) * 80 + quad * 16);
                    oacc[mt][nt] = __builtin_amdgcn_mfma_f32_16x16x32_bf16(pf, vf, oacc[mt][nt], 0, 0, 0);
                }
            }
            // O -> aO (48-row compact, proj A layout)
            #pragma unroll
            for (int mt = 0; mt < 2; ++mt)
                #pragma unroll
                for (int i = 0; i < 4; ++i) {
                    int tok = mt * 16 + q4 + i;
                    if (tok < 24) {
                        int r = win * 24 + tok;
                        #pragma unroll
                        for (int nt = 0; nt < 2; ++nt)
                            aO[r * 200 + h * 32 + nt * 16 + l15] = (bf16_t)oacc[mt][nt][i];
                    }
                }
        } // win
    }
    __syncthreads();

    // ================= proj GEMM (M=48, 2 ntiles/wave) + residual =================
    float rxw[3][2][4];   // f32 residual carried in registers to the final store
    {
        f32x4 pacc[3][2];
        #pragma unroll
        for (int m = 0; m < 3; ++m)
            #pragma unroll
            for (int n = 0; n < 2; ++n) pacc[m][n] = (f32x4){0.f, 0.f, 0.f, 0.f};
        for (int kt = 0; kt < 6; ++kt) {
            bf16x8 af[3];
            #pragma unroll
            for (int m = 0; m < 3; ++m)
                af[m] = *(const bf16x8*)(aOb + (l15 + m * 16) * 400 + kt * 64 + quad * 16);
            #pragma unroll
            for (int n = 0; n < 2; ++n) {
                int NT = wv * 2 + n;
                bf16x8 bfr = *(const bf16x8*)(wf + WF_PROJ + ((NT * 6 + kt) * 64 + lane) * 8);
                #pragma unroll
                for (int m = 0; m < 3; ++m)
                    pacc[m][n] = __builtin_amdgcn_mfma_f32_16x16x32_bf16(af[m], bfr, pacc[m][n], 0, 0, 0);
            }
        }
        __syncthreads();   // all aO reads done before xw2b writes
        #pragma unroll
        for (int n = 0; n < 2; ++n) {
            int c = (wv * 2 + n) * 16 + l15;
            float pb = proj_b[c];
            #pragma unroll
            for (int m = 0; m < 3; ++m)
                #pragma unroll
                for (int i = 0; i < 4; ++i) {
                    int r = m * 16 + q4 + i;
                    float val = x[sRowOff[r] + c] + pb + pacc[m][n][i];
                    rxw[m][n][i] = val;
                    xw2h[r * 200 + c] = (bf16_t)val;
                }
        }
    }
    __syncthreads();

    // ---- LN2 stats from bf16 xw2 copy ----
    {
        int r = t >> 3, l = t & 7;
        float sm = 0.f, s2 = 0.f;
        #pragma unroll
        for (int s = 0; s < 6; ++s) {
            union { bf16_t h[4]; uint2 u; } pk;
            pk.u = *(const uint2*)(xw2b + r * 400 + l * 8 + s * 64);
            #pragma unroll
            for (int z = 0; z < 4; ++z) { float v = (float)pk.h[z]; sm += v; s2 += v * v; }
        }
        sm += __shfl_xor(sm, 1); s2 += __shfl_xor(s2, 1);
        sm += __shfl_xor(sm, 2); s2 += __shfl_xor(s2, 2);
        sm += __shfl_xor(sm, 4); s2 += __shfl_xor(s2, 4);
        if (l == 0) {
            float mu = sm * (1.f / 192.f);
            float var = s2 * (1.f / 192.f) - mu * mu;
            sMu[r] = mu; sRs[r] = rsqrtf(var + 1e-5f);
        }
    }
    __syncthreads();
    // ---- LN2 normalize -> aH2 ----
    for (int p = t; p < 4608; p += 384) {
        int r = p / 96, c2 = p % 96, c = c2 * 2;
        float mu = sMu[r], rs = sRs[r];
        union { bf16_t h[2]; unsigned u; } in, pk;
        in.u = *(const unsigned*)(xw2b + r * 400 + c2 * 4);
        pk.h[0] = (bf16_t)(((float)in.h[0] - mu) * rs * ln2_g[c]     + ln2_b[c]);
        pk.h[1] = (bf16_t)(((float)in.h[1] - mu) * rs * ln2_g[c + 1] + ln2_b[c + 1]);
        *(unsigned*)(aH2b + r * 400 + c2 * 4) = pk.u;
    }
    __syncthreads();

    // ================= MLP: 4 chunks of 192 hidden cols =================
    f32x4 acc2[3][2];
    #pragma unroll
    for (int m = 0; m < 3; ++m)
        #pragma unroll
        for (int n = 0; n < 2; ++n) {
            float b2 = mlp_b2[(wv * 2 + n) * 16 + l15];
            acc2[m][n] = (f32x4){b2, b2, b2, b2};
        }
    for (int ch = 0; ch < 4; ++ch) {
        f32x4 a1[3][2];
        #pragma unroll
        for (int m = 0; m < 3; ++m)
            #pragma unroll
            for (int n = 0; n < 2; ++n) {
                float b1 = mlp_b1[ch * 192 + (wv * 2 + n) * 16 + l15];
                a1[m][n] = (f32x4){b1, b1, b1, b1};
            }
        for (int kt = 0; kt < 6; ++kt) {
            bf16x8 af[3];
            #pragma unroll
            for (int m = 0; m < 3; ++m)
                af[m] = *(const bf16x8*)(aH2b + (l15 + m * 16) * 400 + kt * 64 + quad * 16);
            #pragma unroll
            for (int n = 0; n < 2; ++n) {
                int NT = ch * 12 + wv * 2 + n;
                bf16x8 bfr = *(const bf16x8*)(wf + WF_MLP1 + ((NT * 6 + kt) * 64 + lane) * 8);
                #pragma unroll
                for (int m = 0; m < 3; ++m)
                    a1[m][n] = __builtin_amdgcn_mfma_f32_16x16x32_bf16(af[m], bfr, a1[m][n], 0, 0, 0);
            }
        }
        // exact gelu -> aHid
        #pragma unroll
        for (int n = 0; n < 2; ++n) {
            int c = (wv * 2 + n) * 16 + l15;
            #pragma unroll
            for (int m = 0; m < 3; ++m)
                #pragma unroll
                for (int i = 0; i < 4; ++i) {
                    int r = m * 16 + q4 + i;
                    float v = a1[m][n][i];
                    float g = 0.5f * v * (1.f + erff(v * 0.70710678118654752f));
                    aHid[r * 200 + c] = (bf16_t)g;
                }
        }
        __syncthreads();
        // MLP2 partial over this K chunk
        for (int kt = 0; kt < 6; ++kt) {
            bf16x8 af[3];
            #pragma unroll
            for (int m = 0; m < 3; ++m)
                af[m] = *(const bf16x8*)(aHidb + (l15 + m * 16) * 400 + kt * 64 + quad * 16);
            #pragma unroll
            for (int n = 0; n < 2; ++n) {
                int NT = wv * 2 + n;
                int ktg = ch * 6 + kt;
                bf16x8 bfr = *(const bf16x8*)(wf + WF_MLP2 + ((NT * 24 + ktg) * 64 + lane) * 8);
                #pragma unroll
                for (int m = 0; m < 3; ++m)
                    acc2[m][n] = __builtin_amdgcn_mfma_f32_16x16x32_bf16(af[m], bfr, acc2[m][n], 0, 0, 0);
            }
        }
        __syncthreads();
    }

    // ---- final: out = xw2(regs) + mlp ----
    #pragma unroll
    for (int n = 0; n < 2; ++n) {
        int c = (wv * 2 + n) * 16 + l15;
        #pragma unroll
        for (int m = 0; m < 3; ++m)
            #pragma unroll
            for (int i = 0; i < 4; ++i) {
                int r = m * 16 + q4 + i;
                out[sRowOff[r] + c] = rxw[m][n][i] + acc2[m][n][i];
            }
    }
}

extern "C" void kernel_launch(void* const* d_in, const int* in_sizes, int n_in,
                              void* d_out, int out_size, void* d_ws, size_t ws_size,
                              hipStream_t stream) {
    const float* x          = (const float*)d_in[0];
    const float* ln1_g      = (const float*)d_in[1];
    const float* ln1_b      = (const float*)d_in[2];
    const float* qkv_w      = (const float*)d_in[3];
    const float* qkv_b      = (const float*)d_in[4];
    const float* bias_table = (const float*)d_in[5];
    const float* proj_w     = (const float*)d_in[6];
    const float* proj_b     = (const float*)d_in[7];
    const float* ln2_g      = (const float*)d_in[8];
    const float* ln2_b      = (const float*)d_in[9];
    const float* mlp_w1     = (const float*)d_in[10];
    const float* mlp_b1     = (const float*)d_in[11];
    const float* mlp_w2     = (const float*)d_in[12];
    const float* mlp_b2     = (const float*)d_in[13];
    const int*   rel_index  = (const int*)d_in[14];
    float* out = (float*)d_out;
    bf16_t* wsb = (bf16_t*)d_ws;

    preproc_all<<<(WP_TOT + 255) / 256, 256, 0, stream>>>(qkv_w, proj_w, mlp_w1, mlp_w2, wsb);

    pangu_main<<<NBLK, 384, 0, stream>>>(
        x, ln1_g, ln1_b, qkv_b, bias_table, proj_b, ln2_g, ln2_b,
        mlp_b1, mlp_b2, rel_index, wsb, out);
}

// Round 7
// 505.093 us; speedup vs baseline: 1.2914x; 1.0723x over previous
//
#include <hip/hip_runtime.h>
#include <hip/hip_bf16.h>
#include <math.h>

typedef __bf16 bf16_t;
typedef __bf16 bf16x8 __attribute__((ext_vector_type(8)));
typedef float  f32x4  __attribute__((ext_vector_type(4)));

#define NBLK 2688          // 5376 windows / 2 per block
// pair offsets (1 pair = 2 bf16) of pre-swizzled weights inside d_ws
#define WP_QKV  0
#define WP_PROJ 55296
#define WP_MLP1 73728
#define WP_MLP2 147456
#define WP_TOT  221184
// bf16 element offsets
#define WF_QKV  0
#define WF_PROJ 110592
#define WF_MLP1 147456
#define WF_MLP2 294912

// ---------------- merged weight pre-swizzle: W[K][N] f32 -> B-fragment bf16 ----------------
// frag(nt,kt): dst[((nt*Kt + kt)*64 + lane)*8 + j] = W[kt*32 + (lane>>4)*8 + j][nt*16 + (lane&15)]
__global__ void preproc_all(const float* __restrict__ qkv_w, const float* __restrict__ proj_w,
                            const float* __restrict__ mlp_w1, const float* __restrict__ mlp_w2,
                            bf16_t* __restrict__ dst) {
    int p = blockIdx.x * 256 + threadIdx.x;
    if (p >= WP_TOT) return;
    const float* W; int N, Kt; int q = p;
    if (p < WP_PROJ)      { W = qkv_w;  N = 576; Kt = 6;  }
    else if (p < WP_MLP1) { W = proj_w; N = 192; Kt = 6;  q -= WP_PROJ; }
    else if (p < WP_MLP2) { W = mlp_w1; N = 768; Kt = 6;  q -= WP_MLP1; }
    else                  { W = mlp_w2; N = 192; Kt = 24; q -= WP_MLP2; }
    int j    = (q & 3) * 2;
    int lane = (q >> 2) & 63;
    int kt   = (q >> 8) % Kt;
    int nt   = (q >> 8) / Kt;
    int k = kt * 32 + (lane >> 4) * 8 + j;
    int n = nt * 16 + (lane & 15);
    union { bf16_t h[2]; unsigned u; } pk;
    pk.h[0] = (bf16_t)W[k * N + n];
    pk.h[1] = (bf16_t)W[(k + 1) * N + n];
    *(unsigned*)(dst + p * 2) = pk.u;
}

// ---------------- main fused kernel ----------------
// R6 structure (406us anchor: split-QKV, erff gelu) + MLP full-width restructure.
// Evidence (R1/R3/R6): occupancy pinned at ~17% == 1 block/CU regardless of LDS
// (47K/58K/76K) and regs -> LDS is FREE up to 160KB; optimize per-block critical
// path instead of residency. The MLP held 8 of 14 barriers (2 per 192-col chunk)
// because aHid was a 19.2KB ping buffer. Full-width aHid [48][768(+32 pad)] lets
// MLP1 run all 4 chunks barrier-free (each wave owns its own columns), then ONE
// barrier, then MLP2 as a single 24-iter pipelined K-loop. Loop bodies unchanged
// (R3 lesson: don't restructure bodies, just delete barriers).
//
// LDS arena (115200 B):
//  aA   [0,19200)       bf16 [48][200]  LN1 out / QKV A (compact 48 rows)
//  wavebufs 19200+wv*9344 (attention phase only, dead after):
//      Qb  [24][40] @0     per-window Q (Pb aliases)
//      Kb2 [48][40] @1920  K both windows
//      Vt  [32][56] @5760  V^T both windows (+8 pad cols zeroed)
//  aO   [0,19200)       bf16 [48][200]  attn out / proj A (aliases aA)
//  aH2  [0,19200)       bf16 [48][200]  LN2 out / MLP1 A (aliases aO)
//  xw2b [19200,38400)   bf16 [48][200]  residual1 copy (LN2 input only)
//  aHid [38400,115200)  bf16 [48][800]  FULL 768-col gelu output / MLP2 A
// 115200+576 statics ~= 115.8KB -> 1 block/CU (which we're pinned at anyway).
// NOTE: erff gelu kept (fast_gelu regressed, R5). kt loops NOT pragma-unrolled (R2).
__global__ __launch_bounds__(384, 3)
void pangu_main(const float* __restrict__ x,
                const float* __restrict__ ln1_g, const float* __restrict__ ln1_b,
                const float* __restrict__ qkv_b,
                const float* __restrict__ bias_table,
                const float* __restrict__ proj_b,
                const float* __restrict__ ln2_g, const float* __restrict__ ln2_b,
                const float* __restrict__ mlp_b1, const float* __restrict__ mlp_b2,
                const int* __restrict__ rel_index,
                const bf16_t* __restrict__ wf,
                float* __restrict__ out)
{
    __shared__ __align__(16) unsigned char arena[115200];
    __shared__ int   sRowOff[48];
    __shared__ float sMu[48], sRs[48];

    unsigned char* aAb   = arena;
    unsigned char* aOb   = arena;                 // alias aA (post-QKV barrier)
    unsigned char* aH2b  = arena;                 // alias aO (dead)
    unsigned char* xw2b  = arena + 19200;
    unsigned char* aHidb = arena + 38400;         // full-width [48][800] bf16 (1600B rows)
    bf16_t* aO   = (bf16_t*)aOb;
    bf16_t* aHid = (bf16_t*)aHidb;
    bf16_t* xw2h = (bf16_t*)xw2b;

    const int t    = threadIdx.x;
    const int lane = t & 63;
    const int wv   = t >> 6;          // 0..5 (wave id == head id)
    const int quad = lane >> 4;
    const int l15  = lane & 15;
    const int q4   = quad * 4;

    // ---- row offsets of the 48 tokens (2 windows) ----
    if (t < 48) {
        int win = t / 24, tok = t % 24;
        int W = blockIdx.x * 2 + win;
        int id_ = W % 7;  int r1 = W / 7;
        int iw_ = r1 % 16; int r2 = r1 / 16;
        int ih_ = r2 % 24; int b  = r2 / 24;
        int i = tok / 12, j = (tok % 12) / 2, k = tok % 2;
        sRowOff[t] = (((b * 48 + ih_ * 2 + i) * 96 + iw_ * 6 + j) * 14 + id_ * 2 + k) * 192;
    }
    __syncthreads();

    // ---- LN1 entirely in registers: 8 threads/row, 24 f32 each ----
    {
        int r48 = t >> 3, l = t & 7;
        const float* xr = x + sRowOff[r48];
        float4 v[6];
        #pragma unroll
        for (int s = 0; s < 6; ++s) v[s] = *(const float4*)(xr + l * 4 + s * 32);
        float sm = 0.f, s2 = 0.f;
        #pragma unroll
        for (int s = 0; s < 6; ++s) {
            sm += v[s].x + v[s].y + v[s].z + v[s].w;
            s2 += v[s].x * v[s].x + v[s].y * v[s].y + v[s].z * v[s].z + v[s].w * v[s].w;
        }
        sm += __shfl_xor(sm, 1); s2 += __shfl_xor(s2, 1);
        sm += __shfl_xor(sm, 2); s2 += __shfl_xor(s2, 2);
        sm += __shfl_xor(sm, 4); s2 += __shfl_xor(s2, 4);
        float mu = sm * (1.f / 192.f);
        float var = s2 * (1.f / 192.f) - mu * mu;
        float rs = rsqrtf(var + 1e-5f);
        int row = r48;   // compact 48-row layout
        #pragma unroll
        for (int s = 0; s < 6; ++s) {
            int c = l * 4 + s * 32;
            union { bf16_t h[4]; uint2 u; } pk;
            pk.h[0] = (bf16_t)((v[s].x - mu) * rs * ln1_g[c]     + ln1_b[c]);
            pk.h[1] = (bf16_t)((v[s].y - mu) * rs * ln1_g[c + 1] + ln1_b[c + 1]);
            pk.h[2] = (bf16_t)((v[s].z - mu) * rs * ln1_g[c + 2] + ln1_b[c + 2]);
            pk.h[3] = (bf16_t)((v[s].w - mu) * rs * ln1_g[c + 3] + ln1_b[c + 3]);
            *(uint2*)(aAb + row * 400 + c * 2) = pk.u;
        }
    }
    __syncthreads();

    // ================= QKV GEMM (2 passes) + attention =================
    {
        const int h = wv;
        unsigned char* wb = arena + 19200 + wv * 9344;
        bf16_t* Qb  = (bf16_t*)wb;                 // [24][40] per-win; Pb aliases
        bf16_t* Kb2 = (bf16_t*)(wb + 1920);        // [48][40] both windows
        bf16_t* Vt  = (bf16_t*)(wb + 5760);        // [32][56] both windows (+pad cols)
        bf16_t* Pb  = (bf16_t*)wb;

        // ---- pass 1: K,V ntiles (4 per head), acc[3][4] ----
        {
            f32x4 acc[3][4];
            const int ntg[4] = {12+2*h, 13+2*h, 24+2*h, 25+2*h};
            float bq[4];
            #pragma unroll
            for (int n = 0; n < 4; ++n) bq[n] = qkv_b[ntg[n] * 16 + l15];
            #pragma unroll
            for (int m = 0; m < 3; ++m)
                #pragma unroll
                for (int n = 0; n < 4; ++n)
                    acc[m][n] = (f32x4){bq[n], bq[n], bq[n], bq[n]};
            for (int kt = 0; kt < 6; ++kt) {
                bf16x8 af[3];
                #pragma unroll
                for (int m = 0; m < 3; ++m)
                    af[m] = *(const bf16x8*)(aAb + (l15 + m * 16) * 400 + kt * 64 + quad * 16);
                #pragma unroll
                for (int n = 0; n < 4; ++n) {
                    bf16x8 bfr = *(const bf16x8*)(wf + WF_QKV + ((ntg[n] * 6 + kt) * 64 + lane) * 8);
                    #pragma unroll
                    for (int m = 0; m < 3; ++m)
                        acc[m][n] = __builtin_amdgcn_mfma_f32_16x16x32_bf16(af[m], bfr, acc[m][n], 0, 0, 0);
                }
            }
            // scatter K (both wins) and V^T (both wins); wave-private, no barrier needed
            #pragma unroll
            for (int m = 0; m < 3; ++m)
                #pragma unroll
                for (int i = 0; i < 4; ++i) {
                    int row = m * 16 + q4 + i;   // 0..47 global token
                    #pragma unroll
                    for (int nt = 0; nt < 2; ++nt) {
                        int d = nt * 16 + l15;
                        Kb2[row * 40 + d] = (bf16_t)(acc[m][nt][i]);
                        Vt[d * 56 + row]  = (bf16_t)(acc[m][2+nt][i]);
                    }
                }
            // zero Vt pad cols 48..55 (read by win1's PV k-range; P=0 there but avoid NaN)
            {
                int d = lane >> 1, half = lane & 1;
                *(uint2*)((unsigned char*)Vt + d * 112 + 96 + half * 8) = make_uint2(0u, 0u);
            }
        }

        // ---- pass 2: Q ntiles (2 per head), qacc[3][2] stays live through win loop ----
        f32x4 qacc[3][2];
        {
            const int ntg[2] = {2*h, 2*h+1};
            float bq[2];
            #pragma unroll
            for (int n = 0; n < 2; ++n) bq[n] = qkv_b[ntg[n] * 16 + l15];
            #pragma unroll
            for (int m = 0; m < 3; ++m)
                #pragma unroll
                for (int n = 0; n < 2; ++n)
                    qacc[m][n] = (f32x4){bq[n], bq[n], bq[n], bq[n]};
            for (int kt = 0; kt < 6; ++kt) {
                bf16x8 af[3];
                #pragma unroll
                for (int m = 0; m < 3; ++m)
                    af[m] = *(const bf16x8*)(aAb + (l15 + m * 16) * 400 + kt * 64 + quad * 16);
                #pragma unroll
                for (int n = 0; n < 2; ++n) {
                    bf16x8 bfr = *(const bf16x8*)(wf + WF_QKV + ((ntg[n] * 6 + kt) * 64 + lane) * 8);
                    #pragma unroll
                    for (int m = 0; m < 3; ++m)
                        qacc[m][n] = __builtin_amdgcn_mfma_f32_16x16x32_bf16(af[m], bfr, qacc[m][n], 0, 0, 0);
                }
            }
        }
        __syncthreads();   // all waves done reading aA; aO (alias) written below

        const float scale = 0.1767766952966369f;  // 1/sqrt(32)
        #pragma unroll
        for (int win = 0; win < 2; ++win) {
            // scatter Q (scaled) for this window from qacc
            #pragma unroll
            for (int m = 0; m < 3; ++m)
                #pragma unroll
                for (int i = 0; i < 4; ++i) {
                    int tok = m * 16 + q4 + i - win * 24;
                    if (tok >= 0 && tok < 24) {
                        #pragma unroll
                        for (int nt = 0; nt < 2; ++nt)
                            Qb[tok * 40 + nt * 16 + l15] = (bf16_t)(qacc[m][nt][i] * scale);
                    }
                }
            // S = Qs.K^T + bias  (bias gathered as C-init)
            f32x4 sacc[2][2];
            #pragma unroll
            for (int mt = 0; mt < 2; ++mt)
                #pragma unroll
                for (int nt = 0; nt < 2; ++nt)
                    #pragma unroll
                    for (int i = 0; i < 4; ++i) {
                        int n = mt * 16 + q4 + i; if (n > 23) n = 23;
                        int m = nt * 16 + l15;    if (m > 23) m = 23;
                        sacc[mt][nt][i] = bias_table[rel_index[n * 24 + m] * 6 + h];
                    }
            #pragma unroll
            for (int nt = 0; nt < 2; ++nt) {
                bf16x8 kf = *(const bf16x8*)((unsigned char*)Kb2 + (win * 24 + l15 + nt * 16) * 80 + quad * 16);
                #pragma unroll
                for (int mt = 0; mt < 2; ++mt) {
                    bf16x8 qf = *(const bf16x8*)((unsigned char*)Qb + (l15 + mt * 16) * 80 + quad * 16);
                    sacc[mt][nt] = __builtin_amdgcn_mfma_f32_16x16x32_bf16(qf, kf, sacc[mt][nt], 0, 0, 0);
                }
            }
            // in-register softmax over cols 0..23 (row lives in 16 lanes of one quad)
            #pragma unroll
            for (int mt = 0; mt < 2; ++mt)
                #pragma unroll
                for (int i = 0; i < 4; ++i) {
                    float s0 = sacc[mt][0][i];
                    float s1m = (l15 < 8) ? sacc[mt][1][i] : -1e30f;
                    float mx = fmaxf(s0, s1m);
                    mx = fmaxf(mx, __shfl_xor(mx, 1));
                    mx = fmaxf(mx, __shfl_xor(mx, 2));
                    mx = fmaxf(mx, __shfl_xor(mx, 4));
                    mx = fmaxf(mx, __shfl_xor(mx, 8));
                    float e0 = __expf(s0 - mx);
                    float e1 = (l15 < 8) ? __expf(sacc[mt][1][i] - mx) : 0.f;
                    float sum = e0 + e1;
                    sum += __shfl_xor(sum, 1);
                    sum += __shfl_xor(sum, 2);
                    sum += __shfl_xor(sum, 4);
                    sum += __shfl_xor(sum, 8);
                    float inv = 1.f / sum;
                    sacc[mt][0][i] = e0 * inv;
                    sacc[mt][1][i] = e1 * inv;   // 0 for cols 24..31
                }
            // P -> LDS (A-operand layout; aliases Qb, Q dead for this window)
            #pragma unroll
            for (int mt = 0; mt < 2; ++mt)
                #pragma unroll
                for (int i = 0; i < 4; ++i) {
                    int r = mt * 16 + q4 + i;
                    if (r < 24) {
                        Pb[r * 40 + l15]      = (bf16_t)sacc[mt][0][i];
                        Pb[r * 40 + 16 + l15] = (bf16_t)sacc[mt][1][i];
                    }
                }
            // O = P.V  (Vt cols win*24 .. win*24+31; P=0 beyond 24 real toks)
            f32x4 oacc[2][2];
            #pragma unroll
            for (int mt = 0; mt < 2; ++mt)
                #pragma unroll
                for (int nt = 0; nt < 2; ++nt)
                    oacc[mt][nt] = (f32x4){0.f, 0.f, 0.f, 0.f};
            #pragma unroll
            for (int nt = 0; nt < 2; ++nt) {
                bf16x8 vf = *(const bf16x8*)((unsigned char*)Vt + (l15 + nt * 16) * 112 + win * 48 + quad * 16);
                #pragma unroll
                for (int mt = 0; mt < 2; ++mt) {
                    bf16x8 pf = *(const bf16x8*)((unsigned char*)Pb + (l15 + mt * 16) * 80 + quad * 16);
                    oacc[mt][nt] = __builtin_amdgcn_mfma_f32_16x16x32_bf16(pf, vf, oacc[mt][nt], 0, 0, 0);
                }
            }
            // O -> aO (48-row compact, proj A layout)
            #pragma unroll
            for (int mt = 0; mt < 2; ++mt)
                #pragma unroll
                for (int i = 0; i < 4; ++i) {
                    int tok = mt * 16 + q4 + i;
                    if (tok < 24) {
                        int r = win * 24 + tok;
                        #pragma unroll
                        for (int nt = 0; nt < 2; ++nt)
                            aO[r * 200 + h * 32 + nt * 16 + l15] = (bf16_t)oacc[mt][nt][i];
                    }
                }
        } // win
    }
    __syncthreads();

    // ================= proj GEMM (M=48, 2 ntiles/wave) + residual =================
    float rxw[3][2][4];   // f32 residual carried in registers to the final store
    {
        f32x4 pacc[3][2];
        #pragma unroll
        for (int m = 0; m < 3; ++m)
            #pragma unroll
            for (int n = 0; n < 2; ++n) pacc[m][n] = (f32x4){0.f, 0.f, 0.f, 0.f};
        for (int kt = 0; kt < 6; ++kt) {
            bf16x8 af[3];
            #pragma unroll
            for (int m = 0; m < 3; ++m)
                af[m] = *(const bf16x8*)(aOb + (l15 + m * 16) * 400 + kt * 64 + quad * 16);
            #pragma unroll
            for (int n = 0; n < 2; ++n) {
                int NT = wv * 2 + n;
                bf16x8 bfr = *(const bf16x8*)(wf + WF_PROJ + ((NT * 6 + kt) * 64 + lane) * 8);
                #pragma unroll
                for (int m = 0; m < 3; ++m)
                    pacc[m][n] = __builtin_amdgcn_mfma_f32_16x16x32_bf16(af[m], bfr, pacc[m][n], 0, 0, 0);
            }
        }
        __syncthreads();   // all aO reads done before xw2b writes
        #pragma unroll
        for (int n = 0; n < 2; ++n) {
            int c = (wv * 2 + n) * 16 + l15;
            float pb = proj_b[c];
            #pragma unroll
            for (int m = 0; m < 3; ++m)
                #pragma unroll
                for (int i = 0; i < 4; ++i) {
                    int r = m * 16 + q4 + i;
                    float val = x[sRowOff[r] + c] + pb + pacc[m][n][i];
                    rxw[m][n][i] = val;
                    xw2h[r * 200 + c] = (bf16_t)val;
                }
        }
    }
    __syncthreads();

    // ---- LN2 stats from bf16 xw2 copy ----
    {
        int r = t >> 3, l = t & 7;
        float sm = 0.f, s2 = 0.f;
        #pragma unroll
        for (int s = 0; s < 6; ++s) {
            union { bf16_t h[4]; uint2 u; } pk;
            pk.u = *(const uint2*)(xw2b + r * 400 + l * 8 + s * 64);
            #pragma unroll
            for (int z = 0; z < 4; ++z) { float v = (float)pk.h[z]; sm += v; s2 += v * v; }
        }
        sm += __shfl_xor(sm, 1); s2 += __shfl_xor(s2, 1);
        sm += __shfl_xor(sm, 2); s2 += __shfl_xor(s2, 2);
        sm += __shfl_xor(sm, 4); s2 += __shfl_xor(s2, 4);
        if (l == 0) {
            float mu = sm * (1.f / 192.f);
            float var = s2 * (1.f / 192.f) - mu * mu;
            sMu[r] = mu; sRs[r] = rsqrtf(var + 1e-5f);
        }
    }
    __syncthreads();
    // ---- LN2 normalize -> aH2 ----
    for (int p = t; p < 4608; p += 384) {
        int r = p / 96, c2 = p % 96, c = c2 * 2;
        float mu = sMu[r], rs = sRs[r];
        union { bf16_t h[2]; unsigned u; } in, pk;
        in.u = *(const unsigned*)(xw2b + r * 400 + c2 * 4);
        pk.h[0] = (bf16_t)(((float)in.h[0] - mu) * rs * ln2_g[c]     + ln2_b[c]);
        pk.h[1] = (bf16_t)(((float)in.h[1] - mu) * rs * ln2_g[c + 1] + ln2_b[c + 1]);
        *(unsigned*)(aH2b + r * 400 + c2 * 4) = pk.u;
    }
    __syncthreads();

    // ================= MLP: full-width hidden, 1 internal barrier =================
    // MLP1: 4 chunks back-to-back, no barriers (each wave writes only its own
    // columns of aHid). Then one barrier. Then MLP2 as a single 24-iter K-loop.
    f32x4 acc2[3][2];
    #pragma unroll
    for (int m = 0; m < 3; ++m)
        #pragma unroll
        for (int n = 0; n < 2; ++n) {
            float b2 = mlp_b2[(wv * 2 + n) * 16 + l15];
            acc2[m][n] = (f32x4){b2, b2, b2, b2};
        }
    for (int ch = 0; ch < 4; ++ch) {
        f32x4 a1[3][2];
        #pragma unroll
        for (int m = 0; m < 3; ++m)
            #pragma unroll
            for (int n = 0; n < 2; ++n) {
                float b1 = mlp_b1[ch * 192 + (wv * 2 + n) * 16 + l15];
                a1[m][n] = (f32x4){b1, b1, b1, b1};
            }
        for (int kt = 0; kt < 6; ++kt) {
            bf16x8 af[3];
            #pragma unroll
            for (int m = 0; m < 3; ++m)
                af[m] = *(const bf16x8*)(aH2b + (l15 + m * 16) * 400 + kt * 64 + quad * 16);
            #pragma unroll
            for (int n = 0; n < 2; ++n) {
                int NT = ch * 12 + wv * 2 + n;
                bf16x8 bfr = *(const bf16x8*)(wf + WF_MLP1 + ((NT * 6 + kt) * 64 + lane) * 8);
                #pragma unroll
                for (int m = 0; m < 3; ++m)
                    a1[m][n] = __builtin_amdgcn_mfma_f32_16x16x32_bf16(af[m], bfr, a1[m][n], 0, 0, 0);
            }
        }
        // exact gelu -> aHid full-width columns ch*192 + wave's 32 cols
        #pragma unroll
        for (int n = 0; n < 2; ++n) {
            int c = ch * 192 + (wv * 2 + n) * 16 + l15;
            #pragma unroll
            for (int m = 0; m < 3; ++m)
                #pragma unroll
                for (int i = 0; i < 4; ++i) {
                    int r = m * 16 + q4 + i;
                    float v = a1[m][n][i];
                    float g = 0.5f * v * (1.f + erff(v * 0.70710678118654752f));
                    aHid[r * 800 + c] = (bf16_t)g;
                }
        }
    }
    __syncthreads();
    // MLP2: single 24-iteration pipelined K-loop over the full hidden width
    for (int ktg = 0; ktg < 24; ++ktg) {
        bf16x8 af[3];
        #pragma unroll
        for (int m = 0; m < 3; ++m)
            af[m] = *(const bf16x8*)(aHidb + (l15 + m * 16) * 1600 + ktg * 64 + quad * 16);
        #pragma unroll
        for (int n = 0; n < 2; ++n) {
            int NT = wv * 2 + n;
            bf16x8 bfr = *(const bf16x8*)(wf + WF_MLP2 + ((NT * 24 + ktg) * 64 + lane) * 8);
            #pragma unroll
            for (int m = 0; m < 3; ++m)
                acc2[m][n] = __builtin_amdgcn_mfma_f32_16x16x32_bf16(af[m], bfr, acc2[m][n], 0, 0, 0);
        }
    }

    // ---- final: out = xw2(regs) + mlp ----
    #pragma unroll
    for (int n = 0; n < 2; ++n) {
        int c = (wv * 2 + n) * 16 + l15;
        #pragma unroll
        for (int m = 0; m < 3; ++m)
            #pragma unroll
            for (int i = 0; i < 4; ++i) {
                int r = m * 16 + q4 + i;
                out[sRowOff[r] + c] = rxw[m][n][i] + acc2[m][n][i];
            }
    }
}

extern "C" void kernel_launch(void* const* d_in, const int* in_sizes, int n_in,
                              void* d_out, int out_size, void* d_ws, size_t ws_size,
                              hipStream_t stream) {
    const float* x          = (const float*)d_in[0];
    const float* ln1_g      = (const float*)d_in[1];
    const float* ln1_b      = (const float*)d_in[2];
    const float* qkv_w      = (const float*)d_in[3];
    const float* qkv_b      = (const float*)d_in[4];
    const float* bias_table = (const float*)d_in[5];
    const float* proj_w     = (const float*)d_in[6];
    const float* proj_b     = (const float*)d_in[7];
    const float* ln2_g      = (const float*)d_in[8];
    const float* ln2_b      = (const float*)d_in[9];
    const float* mlp_w1     = (const float*)d_in[10];
    const float* mlp_b1     = (const float*)d_in[11];
    const float* mlp_w2     = (const float*)d_in[12];
    const float* mlp_b2     = (const float*)d_in[13];
    const int*   rel_index  = (const int*)d_in[14];
    float* out = (float*)d_out;
    bf16_t* wsb = (bf16_t*)d_ws;

    preproc_all<<<(WP_TOT + 255) / 256, 256, 0, stream>>>(qkv_w, proj_w, mlp_w1, mlp_w2, wsb);

    pangu_main<<<NBLK, 384, 0, stream>>>(
        x, ln1_g, ln1_b, qkv_b, bias_table, proj_b, ln2_g, ln2_b,
        mlp_b1, mlp_b2, rel_index, wsb, out);
}

// Round 8
// 473.643 us; speedup vs baseline: 1.3772x; 1.0664x over previous
//
#include <hip/hip_runtime.h>
#include <hip/hip_bf16.h>
#include <math.h>

typedef __bf16 bf16_t;
typedef __bf16 bf16x8 __attribute__((ext_vector_type(8)));
typedef float  f32x4  __attribute__((ext_vector_type(4)));

#define NBLK 1344          // 5376 windows / 4 per block
// pair offsets (1 pair = 2 bf16) of pre-swizzled weights inside d_ws
#define WP_QKV  0
#define WP_PROJ 55296
#define WP_MLP1 73728
#define WP_MLP2 147456
#define WP_TOT  221184
// bf16 element offsets
#define WF_QKV  0
#define WF_PROJ 110592
#define WF_MLP1 147456
#define WF_MLP2 294912

// ---------------- merged weight pre-swizzle: W[K][N] f32 -> B-fragment bf16 ----------------
// frag(nt,kt): dst[((nt*Kt + kt)*64 + lane)*8 + j] = W[kt*32 + (lane>>4)*8 + j][nt*16 + (lane&15)]
__global__ void preproc_all(const float* __restrict__ qkv_w, const float* __restrict__ proj_w,
                            const float* __restrict__ mlp_w1, const float* __restrict__ mlp_w2,
                            bf16_t* __restrict__ dst) {
    int p = blockIdx.x * 256 + threadIdx.x;
    if (p >= WP_TOT) return;
    const float* W; int N, Kt; int q = p;
    if (p < WP_PROJ)      { W = qkv_w;  N = 576; Kt = 6;  }
    else if (p < WP_MLP1) { W = proj_w; N = 192; Kt = 6;  q -= WP_PROJ; }
    else if (p < WP_MLP2) { W = mlp_w1; N = 768; Kt = 6;  q -= WP_MLP1; }
    else                  { W = mlp_w2; N = 192; Kt = 24; q -= WP_MLP2; }
    int j    = (q & 3) * 2;
    int lane = (q >> 2) & 63;
    int kt   = (q >> 8) % Kt;
    int nt   = (q >> 8) / Kt;
    int k = kt * 32 + (lane >> 4) * 8 + j;
    int n = nt * 16 + (lane & 15);
    union { bf16_t h[2]; unsigned u; } pk;
    pk.h[0] = (bf16_t)W[k * N + n];
    pk.h[1] = (bf16_t)W[(k + 1) * N + n];
    *(unsigned*)(dst + p * 2) = pk.u;
}

// ---------------- main fused kernel ----------------
// 4-window / 768-thread / 12-wave variant of the R7 381us kernel.
// Evidence: occupancy pinned at 6 waves/CU (1.5/SIMD) for 7 rounds regardless of
// LDS/regs -> add the second "block" of waves INSIDE the block (a single block
// always becomes resident if it fits one CU). wave = (head h=wv>>1, pair g=wv&1);
// wave (h,g) runs exactly the R7 per-wave code on window-pair g (rows 48g..48g+47).
// Loop bodies and register shapes identical to R7; only tile bases gain g offsets.
// 12 waves/CU = 3/SIMD doubles latency hiding; barriers/window 4.5 -> 2.5.
// MLP: 2 chunks of 384 hidden cols; aHid rows 784 B (784/4 mod 32 = 4 -> 2-way
// bank pattern = free; fixes R7's 1600-B-stride 8-way conflict, 15.3M->18.3M).
//
// LDS arena (152064 B):
//  aA    [0,38400)       bf16 [96][200]  LN1 out / QKV A (4 windows compact)
//  wavebufs 38400+wv*9344 (x12 = 112128 B, attention phase only, dead after):
//      Qb  [24][40] @0     per-window Q (Pb aliases)
//      Kb2 [48][40] @1920  K both windows of pair g
//      Vt  [32][56] @5760  V^T both windows (+8 pad cols zeroed)
//  aO    [0,38400)       attn out / proj A (aliases aA)
//  aH2   [0,38400)       LN2 out / MLP A (aliases aO)
//  xw2b  [38400,76800)   bf16 [96][200]  residual1 copy (LN2 input only)
//  aHid  [76800,152064)  bf16 [96][392]  half-width gelu buffer, 784-B rows
// + statics 1152 B -> ~153.2 KB <= 160 KB (R7 proved >64KB static LDS works).
// NOTE: erff gelu (fast_gelu regressed R5); kt loops NOT pragma-unrolled (R2);
// R7's post-proj barrier deleted (xw2 region disjoint from aO -> provably safe).
__global__ __launch_bounds__(768, 3)
void pangu_main(const float* __restrict__ x,
                const float* __restrict__ ln1_g, const float* __restrict__ ln1_b,
                const float* __restrict__ qkv_b,
                const float* __restrict__ bias_table,
                const float* __restrict__ proj_b,
                const float* __restrict__ ln2_g, const float* __restrict__ ln2_b,
                const float* __restrict__ mlp_b1, const float* __restrict__ mlp_b2,
                const int* __restrict__ rel_index,
                const bf16_t* __restrict__ wf,
                float* __restrict__ out)
{
    __shared__ __align__(16) unsigned char arena[152064];
    __shared__ int   sRowOff[96];
    __shared__ float sMu[96], sRs[96];

    unsigned char* aAb   = arena;
    unsigned char* aOb   = arena;                 // alias aA (post-QKV barrier)
    unsigned char* aH2b  = arena;                 // alias aO (dead)
    unsigned char* xw2b  = arena + 38400;
    unsigned char* aHidb = arena + 76800;         // [96][392] bf16, 784-B rows
    bf16_t* aO   = (bf16_t*)aOb;
    bf16_t* aHid = (bf16_t*)aHidb;
    bf16_t* xw2h = (bf16_t*)xw2b;

    const int t    = threadIdx.x;
    const int lane = t & 63;
    const int wv   = t >> 6;          // 0..11
    const int h    = wv >> 1;         // head 0..5
    const int g    = wv & 1;          // window-pair 0..1
    const int quad = lane >> 4;
    const int l15  = lane & 15;
    const int q4   = quad * 4;

    // ---- row offsets of the 96 tokens (4 windows) ----
    if (t < 96) {
        int win = t / 24, tok = t % 24;
        int W = blockIdx.x * 4 + win;
        int id_ = W % 7;  int r1 = W / 7;
        int iw_ = r1 % 16; int r2 = r1 / 16;
        int ih_ = r2 % 24; int b  = r2 / 24;
        int i = tok / 12, j = (tok % 12) / 2, k = tok % 2;
        sRowOff[t] = (((b * 48 + ih_ * 2 + i) * 96 + iw_ * 6 + j) * 14 + id_ * 2 + k) * 192;
    }
    __syncthreads();

    // ---- LN1 entirely in registers: 8 threads/row, 96 rows ----
    {
        int r96 = t >> 3, l = t & 7;
        const float* xr = x + sRowOff[r96];
        float4 v[6];
        #pragma unroll
        for (int s = 0; s < 6; ++s) v[s] = *(const float4*)(xr + l * 4 + s * 32);
        float sm = 0.f, s2 = 0.f;
        #pragma unroll
        for (int s = 0; s < 6; ++s) {
            sm += v[s].x + v[s].y + v[s].z + v[s].w;
            s2 += v[s].x * v[s].x + v[s].y * v[s].y + v[s].z * v[s].z + v[s].w * v[s].w;
        }
        sm += __shfl_xor(sm, 1); s2 += __shfl_xor(s2, 1);
        sm += __shfl_xor(sm, 2); s2 += __shfl_xor(s2, 2);
        sm += __shfl_xor(sm, 4); s2 += __shfl_xor(s2, 4);
        float mu = sm * (1.f / 192.f);
        float var = s2 * (1.f / 192.f) - mu * mu;
        float rs = rsqrtf(var + 1e-5f);
        #pragma unroll
        for (int s = 0; s < 6; ++s) {
            int c = l * 4 + s * 32;
            union { bf16_t h4[4]; uint2 u; } pk;
            pk.h4[0] = (bf16_t)((v[s].x - mu) * rs * ln1_g[c]     + ln1_b[c]);
            pk.h4[1] = (bf16_t)((v[s].y - mu) * rs * ln1_g[c + 1] + ln1_b[c + 1]);
            pk.h4[2] = (bf16_t)((v[s].z - mu) * rs * ln1_g[c + 2] + ln1_b[c + 2]);
            pk.h4[3] = (bf16_t)((v[s].w - mu) * rs * ln1_g[c + 3] + ln1_b[c + 3]);
            *(uint2*)(aAb + r96 * 400 + c * 2) = pk.u;
        }
    }
    __syncthreads();

    // ================= QKV GEMM (2 passes) + attention =================
    // wave (h,g): M tiles {3g,3g+1,3g+2} (rows 48g..48g+47 = windows 2g,2g+1)
    {
        unsigned char* wb = arena + 38400 + wv * 9344;
        bf16_t* Qb  = (bf16_t*)wb;                 // [24][40] per-win; Pb aliases
        bf16_t* Kb2 = (bf16_t*)(wb + 1920);        // [48][40] both windows of pair
        bf16_t* Vt  = (bf16_t*)(wb + 5760);        // [32][56] both windows (+pad)
        bf16_t* Pb  = (bf16_t*)wb;

        // ---- pass 1: K,V ntiles (4 per head), acc[3][4] ----
        {
            f32x4 acc[3][4];
            const int ntg[4] = {12+2*h, 13+2*h, 24+2*h, 25+2*h};
            float bq[4];
            #pragma unroll
            for (int n = 0; n < 4; ++n) bq[n] = qkv_b[ntg[n] * 16 + l15];
            #pragma unroll
            for (int m = 0; m < 3; ++m)
                #pragma unroll
                for (int n = 0; n < 4; ++n)
                    acc[m][n] = (f32x4){bq[n], bq[n], bq[n], bq[n]};
            for (int kt = 0; kt < 6; ++kt) {
                bf16x8 af[3];
                #pragma unroll
                for (int m = 0; m < 3; ++m)
                    af[m] = *(const bf16x8*)(aAb + (l15 + (3*g + m) * 16) * 400 + kt * 64 + quad * 16);
                #pragma unroll
                for (int n = 0; n < 4; ++n) {
                    bf16x8 bfr = *(const bf16x8*)(wf + WF_QKV + ((ntg[n] * 6 + kt) * 64 + lane) * 8);
                    #pragma unroll
                    for (int m = 0; m < 3; ++m)
                        acc[m][n] = __builtin_amdgcn_mfma_f32_16x16x32_bf16(af[m], bfr, acc[m][n], 0, 0, 0);
                }
            }
            // scatter K and V^T (pair-local rows 0..47); wave-private, no barrier
            #pragma unroll
            for (int m = 0; m < 3; ++m)
                #pragma unroll
                for (int i = 0; i < 4; ++i) {
                    int row = m * 16 + q4 + i;   // 0..47 pair-local token
                    #pragma unroll
                    for (int nt = 0; nt < 2; ++nt) {
                        int d = nt * 16 + l15;
                        Kb2[row * 40 + d] = (bf16_t)(acc[m][nt][i]);
                        Vt[d * 56 + row]  = (bf16_t)(acc[m][2+nt][i]);
                    }
                }
            // zero Vt pad cols 48..55
            {
                int d = lane >> 1, half = lane & 1;
                *(uint2*)((unsigned char*)Vt + d * 112 + 96 + half * 8) = make_uint2(0u, 0u);
            }
        }

        // ---- pass 2: Q ntiles (2 per head), qacc[3][2] live through win loop ----
        f32x4 qacc[3][2];
        {
            const int ntg[2] = {2*h, 2*h+1};
            float bq[2];
            #pragma unroll
            for (int n = 0; n < 2; ++n) bq[n] = qkv_b[ntg[n] * 16 + l15];
            #pragma unroll
            for (int m = 0; m < 3; ++m)
                #pragma unroll
                for (int n = 0; n < 2; ++n)
                    qacc[m][n] = (f32x4){bq[n], bq[n], bq[n], bq[n]};
            for (int kt = 0; kt < 6; ++kt) {
                bf16x8 af[3];
                #pragma unroll
                for (int m = 0; m < 3; ++m)
                    af[m] = *(const bf16x8*)(aAb + (l15 + (3*g + m) * 16) * 400 + kt * 64 + quad * 16);
                #pragma unroll
                for (int n = 0; n < 2; ++n) {
                    bf16x8 bfr = *(const bf16x8*)(wf + WF_QKV + ((ntg[n] * 6 + kt) * 64 + lane) * 8);
                    #pragma unroll
                    for (int m = 0; m < 3; ++m)
                        qacc[m][n] = __builtin_amdgcn_mfma_f32_16x16x32_bf16(af[m], bfr, qacc[m][n], 0, 0, 0);
                }
            }
        }
        __syncthreads();   // all waves done reading aA; aO (alias) written below

        const float scale = 0.1767766952966369f;  // 1/sqrt(32)
        #pragma unroll
        for (int w01 = 0; w01 < 2; ++w01) {        // local window within pair g
            // scatter Q (scaled) for this window from qacc
            #pragma unroll
            for (int m = 0; m < 3; ++m)
                #pragma unroll
                for (int i = 0; i < 4; ++i) {
                    int tok = m * 16 + q4 + i - w01 * 24;
                    if (tok >= 0 && tok < 24) {
                        #pragma unroll
                        for (int nt = 0; nt < 2; ++nt)
                            Qb[tok * 40 + nt * 16 + l15] = (bf16_t)(qacc[m][nt][i] * scale);
                    }
                }
            // S = Qs.K^T + bias  (bias gathered as C-init)
            f32x4 sacc[2][2];
            #pragma unroll
            for (int mt = 0; mt < 2; ++mt)
                #pragma unroll
                for (int nt = 0; nt < 2; ++nt)
                    #pragma unroll
                    for (int i = 0; i < 4; ++i) {
                        int n = mt * 16 + q4 + i; if (n > 23) n = 23;
                        int m = nt * 16 + l15;    if (m > 23) m = 23;
                        sacc[mt][nt][i] = bias_table[rel_index[n * 24 + m] * 6 + h];
                    }
            #pragma unroll
            for (int nt = 0; nt < 2; ++nt) {
                bf16x8 kf = *(const bf16x8*)((unsigned char*)Kb2 + (w01 * 24 + l15 + nt * 16) * 80 + quad * 16);
                #pragma unroll
                for (int mt = 0; mt < 2; ++mt) {
                    bf16x8 qf = *(const bf16x8*)((unsigned char*)Qb + (l15 + mt * 16) * 80 + quad * 16);
                    sacc[mt][nt] = __builtin_amdgcn_mfma_f32_16x16x32_bf16(qf, kf, sacc[mt][nt], 0, 0, 0);
                }
            }
            // in-register softmax over cols 0..23
            #pragma unroll
            for (int mt = 0; mt < 2; ++mt)
                #pragma unroll
                for (int i = 0; i < 4; ++i) {
                    float s0 = sacc[mt][0][i];
                    float s1m = (l15 < 8) ? sacc[mt][1][i] : -1e30f;
                    float mx = fmaxf(s0, s1m);
                    mx = fmaxf(mx, __shfl_xor(mx, 1));
                    mx = fmaxf(mx, __shfl_xor(mx, 2));
                    mx = fmaxf(mx, __shfl_xor(mx, 4));
                    mx = fmaxf(mx, __shfl_xor(mx, 8));
                    float e0 = __expf(s0 - mx);
                    float e1 = (l15 < 8) ? __expf(sacc[mt][1][i] - mx) : 0.f;
                    float sum = e0 + e1;
                    sum += __shfl_xor(sum, 1);
                    sum += __shfl_xor(sum, 2);
                    sum += __shfl_xor(sum, 4);
                    sum += __shfl_xor(sum, 8);
                    float inv = 1.f / sum;
                    sacc[mt][0][i] = e0 * inv;
                    sacc[mt][1][i] = e1 * inv;   // 0 for cols 24..31
                }
            // P -> LDS (A-operand layout; aliases Qb, Q dead for this window)
            #pragma unroll
            for (int mt = 0; mt < 2; ++mt)
                #pragma unroll
                for (int i = 0; i < 4; ++i) {
                    int r = mt * 16 + q4 + i;
                    if (r < 24) {
                        Pb[r * 40 + l15]      = (bf16_t)sacc[mt][0][i];
                        Pb[r * 40 + 16 + l15] = (bf16_t)sacc[mt][1][i];
                    }
                }
            // O = P.V
            f32x4 oacc[2][2];
            #pragma unroll
            for (int mt = 0; mt < 2; ++mt)
                #pragma unroll
                for (int nt = 0; nt < 2; ++nt)
                    oacc[mt][nt] = (f32x4){0.f, 0.f, 0.f, 0.f};
            #pragma unroll
            for (int nt = 0; nt < 2; ++nt) {
                bf16x8 vf = *(const bf16x8*)((unsigned char*)Vt + (l15 + nt * 16) * 112 + w01 * 48 + quad * 16);
                #pragma unroll
                for (int mt = 0; mt < 2; ++mt) {
                    bf16x8 pf = *(const bf16x8*)((unsigned char*)Pb + (l15 + mt * 16) * 80 + quad * 16);
                    oacc[mt][nt] = __builtin_amdgcn_mfma_f32_16x16x32_bf16(pf, vf, oacc[mt][nt], 0, 0, 0);
                }
            }
            // O -> aO (96-row compact, proj A layout)
            #pragma unroll
            for (int mt = 0; mt < 2; ++mt)
                #pragma unroll
                for (int i = 0; i < 4; ++i) {
                    int tok = mt * 16 + q4 + i;
                    if (tok < 24) {
                        int r = 48 * g + w01 * 24 + tok;
                        #pragma unroll
                        for (int nt = 0; nt < 2; ++nt)
                            aO[r * 200 + h * 32 + nt * 16 + l15] = (bf16_t)oacc[mt][nt][i];
                    }
                }
        } // w01
    }
    __syncthreads();

    // ================= proj GEMM (wave: 3 m-tiles of pair g, ntiles {2h,2h+1}) =================
    float rxw[3][2][4];   // f32 residual carried in registers to the final store
    {
        f32x4 pacc[3][2];
        #pragma unroll
        for (int m = 0; m < 3; ++m)
            #pragma unroll
            for (int n = 0; n < 2; ++n) pacc[m][n] = (f32x4){0.f, 0.f, 0.f, 0.f};
        for (int kt = 0; kt < 6; ++kt) {
            bf16x8 af[3];
            #pragma unroll
            for (int m = 0; m < 3; ++m)
                af[m] = *(const bf16x8*)(aOb + (l15 + (3*g + m) * 16) * 400 + kt * 64 + quad * 16);
            #pragma unroll
            for (int n = 0; n < 2; ++n) {
                int NT = 2 * h + n;
                bf16x8 bfr = *(const bf16x8*)(wf + WF_PROJ + ((NT * 6 + kt) * 64 + lane) * 8);
                #pragma unroll
                for (int m = 0; m < 3; ++m)
                    pacc[m][n] = __builtin_amdgcn_mfma_f32_16x16x32_bf16(af[m], bfr, pacc[m][n], 0, 0, 0);
            }
        }
        // epilogue straight to xw2 (region disjoint from aO -> no barrier needed)
        #pragma unroll
        for (int n = 0; n < 2; ++n) {
            int c = (2 * h + n) * 16 + l15;
            float pb = proj_b[c];
            #pragma unroll
            for (int m = 0; m < 3; ++m)
                #pragma unroll
                for (int i = 0; i < 4; ++i) {
                    int r = (3*g + m) * 16 + q4 + i;
                    float val = x[sRowOff[r] + c] + pb + pacc[m][n][i];
                    rxw[m][n][i] = val;
                    xw2h[r * 200 + c] = (bf16_t)val;
                }
        }
    }
    __syncthreads();

    // ---- LN2 stats from bf16 xw2 copy (8 threads/row, 96 rows) ----
    {
        int r = t >> 3, l = t & 7;
        float sm = 0.f, s2 = 0.f;
        #pragma unroll
        for (int s = 0; s < 6; ++s) {
            union { bf16_t h4[4]; uint2 u; } pk;
            pk.u = *(const uint2*)(xw2b + r * 400 + l * 8 + s * 64);
            #pragma unroll
            for (int z = 0; z < 4; ++z) { float v = (float)pk.h4[z]; sm += v; s2 += v * v; }
        }
        sm += __shfl_xor(sm, 1); s2 += __shfl_xor(s2, 1);
        sm += __shfl_xor(sm, 2); s2 += __shfl_xor(s2, 2);
        sm += __shfl_xor(sm, 4); s2 += __shfl_xor(s2, 4);
        if (l == 0) {
            float mu = sm * (1.f / 192.f);
            float var = s2 * (1.f / 192.f) - mu * mu;
            sMu[r] = mu; sRs[r] = rsqrtf(var + 1e-5f);
        }
    }
    __syncthreads();
    // ---- LN2 normalize -> aH2 (all proj K-loop reads of aO finished at stats barrier) ----
    for (int p = t; p < 9216; p += 768) {
        int r = p / 96, c2 = p % 96, c = c2 * 2;
        float mu = sMu[r], rs = sRs[r];
        union { bf16_t h2[2]; unsigned u; } in, pk;
        in.u = *(const unsigned*)(xw2b + r * 400 + c2 * 4);
        pk.h2[0] = (bf16_t)(((float)in.h2[0] - mu) * rs * ln2_g[c]     + ln2_b[c]);
        pk.h2[1] = (bf16_t)(((float)in.h2[1] - mu) * rs * ln2_g[c + 1] + ln2_b[c + 1]);
        *(unsigned*)(aH2b + r * 400 + c2 * 4) = pk.u;
    }
    __syncthreads();

    // ================= MLP: 2 chunks of 384 hidden cols =================
    // chunk c: MLP1 wave (h,g): ntiles {c*24+4h..+3} x its 3 m-tiles -> a1[3][4]
    //          -> gelu -> aHid[96][392] (784-B rows, conflict-free) -> barrier
    //          MLP2: 12 k-tiles of chunk, ntiles {2h,2h+1} x 3 m -> acc2[3][2]
    f32x4 acc2[3][2];
    #pragma unroll
    for (int m = 0; m < 3; ++m)
        #pragma unroll
        for (int n = 0; n < 2; ++n) {
            float b2 = mlp_b2[(2 * h + n) * 16 + l15];
            acc2[m][n] = (f32x4){b2, b2, b2, b2};
        }
    for (int ch = 0; ch < 2; ++ch) {
        f32x4 a1[3][4];
        #pragma unroll
        for (int m = 0; m < 3; ++m)
            #pragma unroll
            for (int n = 0; n < 4; ++n) {
                float b1 = mlp_b1[(ch * 24 + 4 * h + n) * 16 + l15];
                a1[m][n] = (f32x4){b1, b1, b1, b1};
            }
        for (int kt = 0; kt < 6; ++kt) {
            bf16x8 af[3];
            #pragma unroll
            for (int m = 0; m < 3; ++m)
                af[m] = *(const bf16x8*)(aH2b + (l15 + (3*g + m) * 16) * 400 + kt * 64 + quad * 16);
            #pragma unroll
            for (int n = 0; n < 4; ++n) {
                int NT = ch * 24 + 4 * h + n;
                bf16x8 bfr = *(const bf16x8*)(wf + WF_MLP1 + ((NT * 6 + kt) * 64 + lane) * 8);
                #pragma unroll
                for (int m = 0; m < 3; ++m)
                    a1[m][n] = __builtin_amdgcn_mfma_f32_16x16x32_bf16(af[m], bfr, a1[m][n], 0, 0, 0);
            }
        }
        // exact gelu -> aHid chunk-local cols (4h+n)*16+l15, rows of pair g
        #pragma unroll
        for (int n = 0; n < 4; ++n) {
            int c = (4 * h + n) * 16 + l15;
            #pragma unroll
            for (int m = 0; m < 3; ++m)
                #pragma unroll
                for (int i = 0; i < 4; ++i) {
                    int r = (3*g + m) * 16 + q4 + i;
                    float v = a1[m][n][i];
                    float gl = 0.5f * v * (1.f + erff(v * 0.70710678118654752f));
                    aHid[r * 392 + c] = (bf16_t)gl;
                }
        }
        __syncthreads();
        // MLP2 partial over this chunk's 12 k-tiles
        for (int ktl = 0; ktl < 12; ++ktl) {
            bf16x8 af[3];
            #pragma unroll
            for (int m = 0; m < 3; ++m)
                af[m] = *(const bf16x8*)(aHidb + (l15 + (3*g + m) * 16) * 784 + ktl * 64 + quad * 16);
            #pragma unroll
            for (int n = 0; n < 2; ++n) {
                int NT = 2 * h + n;
                int ktg = ch * 12 + ktl;
                bf16x8 bfr = *(const bf16x8*)(wf + WF_MLP2 + ((NT * 24 + ktg) * 64 + lane) * 8);
                #pragma unroll
                for (int m = 0; m < 3; ++m)
                    acc2[m][n] = __builtin_amdgcn_mfma_f32_16x16x32_bf16(af[m], bfr, acc2[m][n], 0, 0, 0);
            }
        }
        if (ch == 0) __syncthreads();   // aHid reread safety before chunk 1 overwrite
    }

    // ---- final: out = xw2(regs) + mlp ----
    #pragma unroll
    for (int n = 0; n < 2; ++n) {
        int c = (2 * h + n) * 16 + l15;
        #pragma unroll
        for (int m = 0; m < 3; ++m)
            #pragma unroll
            for (int i = 0; i < 4; ++i) {
                int r = (3*g + m) * 16 + q4 + i;
                out[sRowOff[r] + c] = rxw[m][n][i] + acc2[m][n][i];
            }
    }
}

extern "C" void kernel_launch(void* const* d_in, const int* in_sizes, int n_in,
                              void* d_out, int out_size, void* d_ws, size_t ws_size,
                              hipStream_t stream) {
    const float* x          = (const float*)d_in[0];
    const float* ln1_g      = (const float*)d_in[1];
    const float* ln1_b      = (const float*)d_in[2];
    const float* qkv_w      = (const float*)d_in[3];
    const float* qkv_b      = (const float*)d_in[4];
    const float* bias_table = (const float*)d_in[5];
    const float* proj_w     = (const float*)d_in[6];
    const float* proj_b     = (const float*)d_in[7];
    const float* ln2_g      = (const float*)d_in[8];
    const float* ln2_b      = (const float*)d_in[9];
    const float* mlp_w1     = (const float*)d_in[10];
    const float* mlp_b1     = (const float*)d_in[11];
    const float* mlp_w2     = (const float*)d_in[12];
    const float* mlp_b2     = (const float*)d_in[13];
    const int*   rel_index  = (const int*)d_in[14];
    float* out = (float*)d_out;
    bf16_t* wsb = (bf16_t*)d_ws;

    preproc_all<<<(WP_TOT + 255) / 256, 256, 0, stream>>>(qkv_w, proj_w, mlp_w1, mlp_w2, wsb);

    pangu_main<<<NBLK, 768, 0, stream>>>(
        x, ln1_g, ln1_b, qkv_b, bias_table, proj_b, ln2_g, ln2_b,
        mlp_b1, mlp_b2, rel_index, wsb, out);
}